// Round 1
// baseline (492.872 us; speedup 1.0000x reference)
//
#include <hip/hip_runtime.h>
#include <math.h>

typedef __attribute__((ext_vector_type(8))) short short8;
typedef __attribute__((ext_vector_type(4))) float f32x4;
typedef __attribute__((ext_vector_type(4))) float fvec4;
typedef __attribute__((ext_vector_type(4))) unsigned short us4;

#define DI __device__ __forceinline__

constexpr int BB = 2, SS = 2048, HIDc = 2048, NHc = 16, HDc = 128;
constexpr int MT = BB * SS;     // 4096 tokens
constexpr int KC = HIDc;        // 2048 inner dim

// ---- workspace layout (bytes) ----
constexpr size_t OFF_HB  = 0;                                      // H bf16   [4096][2048]
constexpr size_t OFF_WB  = OFF_HB + (size_t)MT * KC * 2;           // W bf16   4x[2048][2048]
constexpr size_t OFF_Q   = OFF_WB + (size_t)4 * HIDc * KC * 2;     // Q bf16   [b][h][s][d]
constexpr size_t OFF_K   = OFF_Q  + (size_t)BB * NHc * SS * HDc * 2;
constexpr size_t OFF_V   = OFF_K  + (size_t)BB * NHc * SS * HDc * 2; // V bf16 [b][h][d][s] (transposed!)
constexpr size_t OFF_ATT = OFF_V  + (size_t)BB * NHc * SS * HDc * 2; // attn bf16 [b*s][hid]
constexpr size_t OFF_COS = OFF_ATT + (size_t)MT * HIDc * 2;
constexpr size_t OFF_SIN = OFF_COS + (size_t)SS * 32 * 4;
constexpr size_t WS_NEED = OFF_SIN + (size_t)SS * 32 * 4;          // ~118 MB

DI float bf2f(unsigned short u) { union { unsigned u; float f; } v; v.u = (unsigned)u << 16; return v.f; }
DI unsigned short f2bf(float f) {
  union { float f; unsigned u; } v; v.f = f;
  unsigned r = v.u + 0x7fffu + ((v.u >> 16) & 1u);
  return (unsigned short)(r >> 16);
}

DI void gload_lds16(const void* g, void* l) {
  __builtin_amdgcn_global_load_lds((const __attribute__((address_space(1))) void*)g,
                                   (__attribute__((address_space(3))) void*)l, 16, 0, 0);
}

// ---------------------------------------------------------------------------
// 1) fp32 -> bf16 convert of H and the 4 weights into one contiguous region
// ---------------------------------------------------------------------------
__global__ void __launch_bounds__(256) cvt_kernel(
    const float* __restrict__ H,  const float* __restrict__ W0,
    const float* __restrict__ W1, const float* __restrict__ W2,
    const float* __restrict__ W3, unsigned short* __restrict__ dst)
{
  constexpr size_t HN = (size_t)MT * KC;      // 8388608
  constexpr size_t WN = (size_t)HIDc * KC;    // 4194304 = 2^22
  size_t e0 = ((size_t)blockIdx.x * 256 + threadIdx.x) * 8;
  const float* src; size_t off;
  if (e0 < HN) { src = H; off = e0; }
  else {
    size_t t = e0 - HN; int a = (int)(t >> 22);
    src = (a == 0) ? W0 : (a == 1) ? W1 : (a == 2) ? W2 : W3;
    off = t & (WN - 1);
  }
  fvec4 v0 = *(const fvec4*)(src + off);
  fvec4 v1 = *(const fvec4*)(src + off + 4);
  short8 o;
  o[0] = (short)f2bf(v0[0]); o[1] = (short)f2bf(v0[1]);
  o[2] = (short)f2bf(v0[2]); o[3] = (short)f2bf(v0[3]);
  o[4] = (short)f2bf(v1[0]); o[5] = (short)f2bf(v1[1]);
  o[6] = (short)f2bf(v1[2]); o[7] = (short)f2bf(v1[3]);
  *(short8*)(dst + e0) = o;
}

// ---------------------------------------------------------------------------
// 2) RoPE tables: theta(t, j) = t * 10000^(-(j mod 32)/32), j = pair idx 0..63
// ---------------------------------------------------------------------------
__global__ void __launch_bounds__(256) rope_tab_kernel(float* __restrict__ cosT,
                                                       float* __restrict__ sinT)
{
  int idx = blockIdx.x * 256 + threadIdx.x;   // S*32 = 65536
  int t = idx >> 5, fi = idx & 31;
  float inv = powf(10000.0f, -(float)fi * (1.0f / 32.0f));
  float ang = (float)t * inv;
  cosT[idx] = cosf(ang);
  sinT[idx] = sinf(ang);
}

// ---------------------------------------------------------------------------
// 3) bf16 GEMM, C[m][n] = sum_k A[m][k] B[n][k]   (both K-contiguous)
//    m97 structure: 128x128 tile, BK=32, 4 waves (2x2), global_load_lds(16B),
//    double-buffered LDS, one barrier per K-step.
//    EPI 0: QKV epilogue (z=0 Q, z=1 K as [b][h][s][d]; z=2 V as [b][h][d][s])
//    EPI 1: fp32 row-major out
// ---------------------------------------------------------------------------
template<int EPI>
__global__ void __launch_bounds__(256) gemm_bt(
    const unsigned short* __restrict__ A,
    const unsigned short* __restrict__ Bw,
    void* __restrict__ dq, void* __restrict__ dk, void* __restrict__ dv)
{
  __shared__ __align__(16) unsigned short As[2][128 * 32];
  __shared__ __align__(16) unsigned short Bs[2][128 * 32];
  const int tid = threadIdx.x, lane = tid & 63, w = tid >> 6;
  const int wy = w >> 1, wx = w & 1;
  const int ln15 = lane & 15, lq = lane >> 4;
  const int n0 = blockIdx.x * 128, m0 = blockIdx.y * 128;
  if (EPI == 0) Bw += (size_t)blockIdx.z * HIDc * KC;

  f32x4 acc[4][4] = {};

  auto stage = [&](int kt, int buf) {
#pragma unroll
    for (int p = 0; p < 2; ++p) {
      int c = p * 256 + w * 64 + lane;           // 16B chunk id within tile
      int row = c >> 2, k0 = (c & 3) << 3;
      const unsigned short* ga = A  + (size_t)(m0 + row) * KC + kt * 32 + k0;
      const unsigned short* gb = Bw + (size_t)(n0 + row) * KC + kt * 32 + k0;
      unsigned short* la = &As[buf][(p * 256 + w * 64) * 8];  // wave-uniform base
      unsigned short* lb = &Bs[buf][(p * 256 + w * 64) * 8];
      gload_lds16(ga, la);
      gload_lds16(gb, lb);
    }
  };

  stage(0, 0);
  __syncthreads();
  constexpr int KT = KC / 32;
  for (int kt = 0; kt < KT; ++kt) {
    int cur = kt & 1;
    if (kt + 1 < KT) stage(kt + 1, cur ^ 1);
    short8 af[4], bfr[4];
#pragma unroll
    for (int i = 0; i < 4; ++i)
      af[i] = *(const short8*)&As[cur][(wy * 64 + i * 16 + ln15) * 32 + lq * 8];
#pragma unroll
    for (int j = 0; j < 4; ++j)
      bfr[j] = *(const short8*)&Bs[cur][(wx * 64 + j * 16 + ln15) * 32 + lq * 8];
#pragma unroll
    for (int i = 0; i < 4; ++i)
#pragma unroll
      for (int j = 0; j < 4; ++j)
        acc[i][j] = __builtin_amdgcn_mfma_f32_16x16x32_bf16(af[i], bfr[j], acc[i][j], 0, 0, 0);
    __syncthreads();
  }

  if (EPI == 0) {
    const int z = blockIdx.z;
    const int b = m0 >> 11;           // token-tile lies in one batch (2048 % 128 == 0)
    const int srow = m0 & 2047;
    if (z == 2) {
      unsigned short* V = (unsigned short*)dv;
#pragma unroll
      for (int i = 0; i < 4; ++i)
#pragma unroll
        for (int j = 0; j < 4; ++j) {
          int s0 = srow + wy * 64 + i * 16 + lq * 4;
          int col = n0 + wx * 64 + j * 16 + ln15;
          int h = col >> 7, d = col & 127;
          size_t ad = (((size_t)b * NHc + h) * HDc + d) * SS + s0;
          us4 pk;
#pragma unroll
          for (int r = 0; r < 4; ++r) pk[r] = f2bf(acc[i][j][r]);
          *(us4*)((unsigned short*)V + ad) = pk;
        }
    } else {
      unsigned short* D = (unsigned short*)(z ? dk : dq);
#pragma unroll
      for (int i = 0; i < 4; ++i)
#pragma unroll
        for (int j = 0; j < 4; ++j)
#pragma unroll
          for (int r = 0; r < 4; ++r) {
            int s = srow + wy * 64 + i * 16 + lq * 4 + r;
            int col = n0 + wx * 64 + j * 16 + ln15;
            int h = col >> 7, d = col & 127;
            D[(((size_t)b * NHc + h) * SS + s) * HDc + d] = f2bf(acc[i][j][r]);
          }
    }
  } else {
    float* O = (float*)dq;
#pragma unroll
    for (int i = 0; i < 4; ++i)
#pragma unroll
      for (int j = 0; j < 4; ++j)
#pragma unroll
        for (int r = 0; r < 4; ++r) {
          int m = m0 + wy * 64 + i * 16 + lq * 4 + r;
          int n = n0 + wx * 64 + j * 16 + ln15;
          O[(size_t)m * HIDc + n] = acc[i][j][r];
        }
  }
}

// ---------------------------------------------------------------------------
// 4) in-place interleaved RoPE on Q and K ([b][h][s][d] bf16, pairs (2j,2j+1))
// ---------------------------------------------------------------------------
__global__ void __launch_bounds__(256) rope_kernel(
    unsigned int* __restrict__ Q, unsigned int* __restrict__ Kd,
    const float* __restrict__ cosT, const float* __restrict__ sinT)
{
  constexpr size_t NP = (size_t)BB * NHc * SS * 64;   // pairs per tensor
  size_t gid = (size_t)blockIdx.x * 256 + threadIdx.x;
  unsigned int* P = (gid < NP) ? Q : Kd;
  size_t r = (gid < NP) ? gid : gid - NP;
  int j  = (int)(r & 63);
  int s  = (int)((r >> 6) & (SS - 1));
  int fi = j & 31;
  float c  = cosT[s * 32 + fi];
  float sn = sinT[s * 32 + fi];
  unsigned v = P[r];
  float x1 = bf2f((unsigned short)(v & 0xffff));
  float x2 = bf2f((unsigned short)(v >> 16));
  float y1 = x1 * c - x2 * sn;
  float y2 = x1 * sn + x2 * c;
  P[r] = (unsigned)f2bf(y1) | ((unsigned)f2bf(y2) << 16);
}

// ---------------------------------------------------------------------------
// 5) causal flash attention.  grid (S/128, B*NH), 256 thr = 4 waves.
//    Each wave owns 32 q-rows (Q frags in regs); K/V tiles (64 kv) staged in
//    XOR-swizzled LDS; P staged per-wave in swizzled LDS; online softmax.
//    Output -> attn bf16 [b*s][hid].
// ---------------------------------------------------------------------------
__global__ void __launch_bounds__(256) attn_kernel(
    const unsigned short* __restrict__ Qg,
    const unsigned short* __restrict__ Kg,
    const unsigned short* __restrict__ Vg,   // [b][h][d][s]
    unsigned short* __restrict__ Og)
{
  __shared__ __align__(16) unsigned short Klds[64 * 128];   // [kv][d] swizzled
  __shared__ __align__(16) unsigned short Vlds[128 * 64];   // [d][kv] swizzled
  __shared__ __align__(16) unsigned short Plds[4][32 * 64]; // per-wave
  const int tid = threadIdx.x, lane = tid & 63, w = tid >> 6;
  const int ln15 = lane & 15, lq = lane >> 4;
  const int qt = blockIdx.x, bh = blockIdx.y;
  const size_t hbase = (size_t)bh * SS * HDc;
  const int q0w = qt * 128 + w * 32;
  const float CE = 1.44269504089f * 0.08838834764831845f;  // log2(e)/sqrt(128)

  short8 aq[2][4];
#pragma unroll
  for (int i = 0; i < 2; ++i)
#pragma unroll
    for (int kf = 0; kf < 4; ++kf)
      aq[i][kf] = *(const short8*)(Qg + hbase + (size_t)(q0w + i * 16 + ln15) * HDc + kf * 32 + lq * 8);

  f32x4 accO[2][8] = {};
  float mr[2][4], lr[2][4];
#pragma unroll
  for (int i = 0; i < 2; ++i)
#pragma unroll
    for (int r = 0; r < 4; ++r) { mr[i][r] = -1e30f; lr[i][r] = 0.f; }

  const int ntiles = 2 * qt + 2;
  for (int kvt = 0; kvt < ntiles; ++kvt) {
    const int kv0 = kvt * 64;
    __syncthreads();
#pragma unroll
    for (int p = 0; p < 4; ++p) {            // K tile: 64 rows x 128 d
      int c = p * 256 + tid;
      int row = c >> 4, sl = c & 15;
      short8 v = *(const short8*)(Kg + hbase + (size_t)(kv0 + row) * HDc + sl * 8);
      *(short8*)&Klds[row * 128 + ((sl ^ (row & 7)) << 3)] = v;
    }
#pragma unroll
    for (int p = 0; p < 4; ++p) {            // V^T tile: 128 d x 64 kv
      int c = p * 256 + tid;
      int d = c >> 3, sl = c & 7;
      short8 v = *(const short8*)(Vg + hbase + (size_t)d * SS + kv0 + sl * 8);
      *(short8*)&Vlds[d * 64 + ((sl ^ (d & 7)) << 3)] = v;
    }
    __syncthreads();
    if (kv0 > q0w + 31) continue;            // beyond this wave's causal range

    // S = Q K^T (raw, unscaled)
    f32x4 sf[2][4] = {};
#pragma unroll
    for (int kf = 0; kf < 4; ++kf)
#pragma unroll
      for (int j = 0; j < 4; ++j) {
        int kvrow = j * 16 + ln15;
        short8 bk = *(const short8*)&Klds[kvrow * 128 + (((kf * 4 + lq) ^ (kvrow & 7)) << 3)];
        sf[0][j] = __builtin_amdgcn_mfma_f32_16x16x32_bf16(aq[0][kf], bk, sf[0][j], 0, 0, 0);
        sf[1][j] = __builtin_amdgcn_mfma_f32_16x16x32_bf16(aq[1][kf], bk, sf[1][j], 0, 0, 0);
      }

    if (kv0 + 63 > q0w) {                    // diagonal: causal mask
#pragma unroll
      for (int i = 0; i < 2; ++i)
#pragma unroll
        for (int j = 0; j < 4; ++j)
#pragma unroll
          for (int r = 0; r < 4; ++r) {
            int qr = q0w + i * 16 + lq * 4 + r;
            int kc = kv0 + j * 16 + ln15;
            if (kc > qr) sf[i][j][r] = -1e30f;
          }
    }

    float al[2][4];
#pragma unroll
    for (int i = 0; i < 2; ++i)
#pragma unroll
      for (int r = 0; r < 4; ++r) {
        float v = fmaxf(fmaxf(sf[i][0][r], sf[i][1][r]), fmaxf(sf[i][2][r], sf[i][3][r]));
        v = fmaxf(v, __shfl_xor(v, 1));
        v = fmaxf(v, __shfl_xor(v, 2));
        v = fmaxf(v, __shfl_xor(v, 4));
        v = fmaxf(v, __shfl_xor(v, 8));
        float mn = fmaxf(mr[i][r], v);
        al[i][r] = exp2f(CE * (mr[i][r] - mn));
        mr[i][r] = mn;
      }
#pragma unroll
    for (int i = 0; i < 2; ++i)
#pragma unroll
      for (int r = 0; r < 4; ++r) {
        float sum = 0.f;
#pragma unroll
        for (int j = 0; j < 4; ++j) {
          float p = exp2f(CE * (sf[i][j][r] - mr[i][r]));
          sf[i][j][r] = p;
          sum += p;
        }
        sum += __shfl_xor(sum, 1); sum += __shfl_xor(sum, 2);
        sum += __shfl_xor(sum, 4); sum += __shfl_xor(sum, 8);
        lr[i][r] = lr[i][r] * al[i][r] + sum;
      }
    // P -> per-wave swizzled LDS (bf16)
#pragma unroll
    for (int i = 0; i < 2; ++i)
#pragma unroll
      for (int j = 0; j < 4; ++j)
#pragma unroll
        for (int r = 0; r < 4; ++r) {
          int prow = i * 16 + lq * 4 + r;
          int pcol = j * 16 + ln15;
          Plds[w][prow * 64 + (pcol ^ ((prow & 7) << 3))] = f2bf(sf[i][j][r]);
        }
    // O rescale
#pragma unroll
    for (int i = 0; i < 2; ++i)
#pragma unroll
      for (int jn = 0; jn < 8; ++jn)
#pragma unroll
        for (int r = 0; r < 4; ++r)
          accO[i][jn][r] *= al[i][r];
    // PV
    short8 ap[2][2];
#pragma unroll
    for (int i = 0; i < 2; ++i)
#pragma unroll
      for (int kp = 0; kp < 2; ++kp) {
        int prow = i * 16 + ln15;
        int pcol = kp * 32 + lq * 8;
        ap[i][kp] = *(const short8*)&Plds[w][prow * 64 + (pcol ^ ((prow & 7) << 3))];
      }
#pragma unroll
    for (int jn = 0; jn < 8; ++jn) {
      int d = jn * 16 + ln15;
#pragma unroll
      for (int kp = 0; kp < 2; ++kp) {
        short8 bv = *(const short8*)&Vlds[d * 64 + (((kp * 4 + lq) ^ (d & 7)) << 3)];
        accO[0][jn] = __builtin_amdgcn_mfma_f32_16x16x32_bf16(ap[0][kp], bv, accO[0][jn], 0, 0, 0);
        accO[1][jn] = __builtin_amdgcn_mfma_f32_16x16x32_bf16(ap[1][kp], bv, accO[1][jn], 0, 0, 0);
      }
    }
  }

  float il[2][4];
#pragma unroll
  for (int i = 0; i < 2; ++i)
#pragma unroll
    for (int r = 0; r < 4; ++r) il[i][r] = 1.0f / lr[i][r];
  const int b = bh >> 4, h = bh & 15;
#pragma unroll
  for (int i = 0; i < 2; ++i)
#pragma unroll
    for (int jn = 0; jn < 8; ++jn)
#pragma unroll
      for (int r = 0; r < 4; ++r) {
        int q = q0w + i * 16 + lq * 4 + r;
        int d = jn * 16 + ln15;
        Og[((size_t)b * SS + q) * HIDc + h * HDc + d] = f2bf(accO[i][jn][r] * il[i][r]);
      }
}

// ---------------------------------------------------------------------------
extern "C" void kernel_launch(void* const* d_in, const int* in_sizes, int n_in,
                              void* d_out, int out_size, void* d_ws, size_t ws_size,
                              hipStream_t stream)
{
  if (ws_size < WS_NEED) return;  // diagnostic: leaves out zeroed -> absmax 3.53

  const float* H  = (const float*)d_in[0];
  const float* Wq = (const float*)d_in[1];
  const float* Wk = (const float*)d_in[2];
  const float* Wv = (const float*)d_in[3];
  const float* Wo = (const float*)d_in[4];
  char* ws = (char*)d_ws;
  unsigned short* HB = (unsigned short*)(ws + OFF_HB);
  unsigned short* WB = (unsigned short*)(ws + OFF_WB);
  unsigned short* Qb = (unsigned short*)(ws + OFF_Q);
  unsigned short* Kb = (unsigned short*)(ws + OFF_K);
  unsigned short* Vb = (unsigned short*)(ws + OFF_V);
  unsigned short* AT = (unsigned short*)(ws + OFF_ATT);
  float* cosT = (float*)(ws + OFF_COS);
  float* sinT = (float*)(ws + OFF_SIN);

  cvt_kernel<<<12288, 256, 0, stream>>>(H, Wq, Wk, Wv, Wo, HB);
  rope_tab_kernel<<<256, 256, 0, stream>>>(cosT, sinT);
  gemm_bt<0><<<dim3(16, 32, 3), 256, 0, stream>>>(HB, WB, Qb, Kb, Vb);
  rope_kernel<<<32768, 256, 0, stream>>>((unsigned*)Qb, (unsigned*)Kb, cosT, sinT);
  attn_kernel<<<dim3(16, 32), 256, 0, stream>>>(Qb, Kb, Vb, AT);
  gemm_bt<1><<<dim3(16, 32, 1), 256, 0, stream>>>(AT, WB + (size_t)3 * HIDc * KC,
                                                  d_out, nullptr, nullptr);
}

// Round 2
// 482.651 us; speedup vs baseline: 1.0212x; 1.0212x over previous
//
#include <hip/hip_runtime.h>
#include <math.h>

typedef __attribute__((ext_vector_type(8))) short short8;
typedef __attribute__((ext_vector_type(4))) float f32x4;
typedef __attribute__((ext_vector_type(4))) float fvec4;
typedef __attribute__((ext_vector_type(4))) unsigned short us4;

#define DI __device__ __forceinline__

constexpr int BB = 2, SS = 2048, HIDc = 2048, NHc = 16, HDc = 128;
constexpr int MT = BB * SS;     // 4096 tokens
constexpr int KC = HIDc;        // 2048 inner dim

// ---- workspace layout (bytes) ----
constexpr size_t OFF_HB  = 0;                                      // H bf16   [4096][2048]
constexpr size_t OFF_WB  = OFF_HB + (size_t)MT * KC * 2;           // W bf16   4x[2048][2048]
constexpr size_t OFF_Q   = OFF_WB + (size_t)4 * HIDc * KC * 2;     // Q bf16   [b][h][s][d]
constexpr size_t OFF_K   = OFF_Q  + (size_t)BB * NHc * SS * HDc * 2;
constexpr size_t OFF_V   = OFF_K  + (size_t)BB * NHc * SS * HDc * 2; // V bf16 [b][h][d][s] (transposed!)
constexpr size_t OFF_ATT = OFF_V  + (size_t)BB * NHc * SS * HDc * 2; // attn bf16 [b*s][hid]
constexpr size_t OFF_COS = OFF_ATT + (size_t)MT * HIDc * 2;
constexpr size_t OFF_SIN = OFF_COS + (size_t)SS * 32 * 4;
constexpr size_t WS_NEED = OFF_SIN + (size_t)SS * 32 * 4;          // ~118 MB

DI float bf2f(unsigned short u) { union { unsigned u; float f; } v; v.u = (unsigned)u << 16; return v.f; }
DI unsigned short f2bf(float f) {
  union { float f; unsigned u; } v; v.f = f;
  unsigned r = v.u + 0x7fffu + ((v.u >> 16) & 1u);
  return (unsigned short)(r >> 16);
}

DI void gload_lds16(const void* g, void* l) {
  __builtin_amdgcn_global_load_lds((const __attribute__((address_space(1))) void*)g,
                                   (__attribute__((address_space(3))) void*)l, 16, 0, 0);
}

// ---------------------------------------------------------------------------
// 1) fp32 -> bf16 convert of H and the 4 weights into one contiguous region
// ---------------------------------------------------------------------------
__global__ void __launch_bounds__(256) cvt_kernel(
    const float* __restrict__ H,  const float* __restrict__ W0,
    const float* __restrict__ W1, const float* __restrict__ W2,
    const float* __restrict__ W3, unsigned short* __restrict__ dst)
{
  constexpr size_t HN = (size_t)MT * KC;      // 8388608
  constexpr size_t WN = (size_t)HIDc * KC;    // 4194304 = 2^22
  size_t e0 = ((size_t)blockIdx.x * 256 + threadIdx.x) * 8;
  const float* src; size_t off;
  if (e0 < HN) { src = H; off = e0; }
  else {
    size_t t = e0 - HN; int a = (int)(t >> 22);
    src = (a == 0) ? W0 : (a == 1) ? W1 : (a == 2) ? W2 : W3;
    off = t & (WN - 1);
  }
  fvec4 v0 = *(const fvec4*)(src + off);
  fvec4 v1 = *(const fvec4*)(src + off + 4);
  short8 o;
  o[0] = (short)f2bf(v0[0]); o[1] = (short)f2bf(v0[1]);
  o[2] = (short)f2bf(v0[2]); o[3] = (short)f2bf(v0[3]);
  o[4] = (short)f2bf(v1[0]); o[5] = (short)f2bf(v1[1]);
  o[6] = (short)f2bf(v1[2]); o[7] = (short)f2bf(v1[3]);
  *(short8*)(dst + e0) = o;
}

// ---------------------------------------------------------------------------
// 2) RoPE tables
// ---------------------------------------------------------------------------
__global__ void __launch_bounds__(256) rope_tab_kernel(float* __restrict__ cosT,
                                                       float* __restrict__ sinT)
{
  int idx = blockIdx.x * 256 + threadIdx.x;   // S*32 = 65536
  int t = idx >> 5, fi = idx & 31;
  float inv = powf(10000.0f, -(float)fi * (1.0f / 32.0f));
  float ang = (float)t * inv;
  cosT[idx] = cosf(ang);
  sinT[idx] = sinf(ang);
}

// ---------------------------------------------------------------------------
// 3) bf16 GEMM (m97 structure, 128x128 tile, BK=32, dbuf LDS, global_load_lds)
// ---------------------------------------------------------------------------
template<int EPI>
__global__ void __launch_bounds__(256) gemm_bt(
    const unsigned short* __restrict__ A,
    const unsigned short* __restrict__ Bw,
    void* __restrict__ dq, void* __restrict__ dk, void* __restrict__ dv)
{
  __shared__ __align__(16) unsigned short As[2][128 * 32];
  __shared__ __align__(16) unsigned short Bs[2][128 * 32];
  const int tid = threadIdx.x, lane = tid & 63, w = tid >> 6;
  const int wy = w >> 1, wx = w & 1;
  const int ln15 = lane & 15, lq = lane >> 4;
  const int n0 = blockIdx.x * 128, m0 = blockIdx.y * 128;
  if (EPI == 0) Bw += (size_t)blockIdx.z * HIDc * KC;

  f32x4 acc[4][4] = {};

  auto stage = [&](int kt, int buf) {
#pragma unroll
    for (int p = 0; p < 2; ++p) {
      int c = p * 256 + w * 64 + lane;           // 16B chunk id within tile
      int row = c >> 2, k0 = (c & 3) << 3;
      const unsigned short* ga = A  + (size_t)(m0 + row) * KC + kt * 32 + k0;
      const unsigned short* gb = Bw + (size_t)(n0 + row) * KC + kt * 32 + k0;
      unsigned short* la = &As[buf][(p * 256 + w * 64) * 8];  // wave-uniform base
      unsigned short* lb = &Bs[buf][(p * 256 + w * 64) * 8];
      gload_lds16(ga, la);
      gload_lds16(gb, lb);
    }
  };

  stage(0, 0);
  __syncthreads();
  constexpr int KT = KC / 32;
  for (int kt = 0; kt < KT; ++kt) {
    int cur = kt & 1;
    if (kt + 1 < KT) stage(kt + 1, cur ^ 1);
    short8 af[4], bfr[4];
#pragma unroll
    for (int i = 0; i < 4; ++i)
      af[i] = *(const short8*)&As[cur][(wy * 64 + i * 16 + ln15) * 32 + lq * 8];
#pragma unroll
    for (int j = 0; j < 4; ++j)
      bfr[j] = *(const short8*)&Bs[cur][(wx * 64 + j * 16 + ln15) * 32 + lq * 8];
#pragma unroll
    for (int i = 0; i < 4; ++i)
#pragma unroll
      for (int j = 0; j < 4; ++j)
        acc[i][j] = __builtin_amdgcn_mfma_f32_16x16x32_bf16(af[i], bfr[j], acc[i][j], 0, 0, 0);
    __syncthreads();
  }

  if (EPI == 0) {
    const int z = blockIdx.z;
    const int b = m0 >> 11;
    const int srow = m0 & 2047;
    if (z == 2) {
      unsigned short* V = (unsigned short*)dv;
#pragma unroll
      for (int i = 0; i < 4; ++i)
#pragma unroll
        for (int j = 0; j < 4; ++j) {
          int s0 = srow + wy * 64 + i * 16 + lq * 4;
          int col = n0 + wx * 64 + j * 16 + ln15;
          int h = col >> 7, d = col & 127;
          size_t ad = (((size_t)b * NHc + h) * HDc + d) * SS + s0;
          us4 pk;
#pragma unroll
          for (int r = 0; r < 4; ++r) pk[r] = f2bf(acc[i][j][r]);
          *(us4*)((unsigned short*)V + ad) = pk;
        }
    } else {
      unsigned short* D = (unsigned short*)(z ? dk : dq);
#pragma unroll
      for (int i = 0; i < 4; ++i)
#pragma unroll
        for (int j = 0; j < 4; ++j)
#pragma unroll
          for (int r = 0; r < 4; ++r) {
            int s = srow + wy * 64 + i * 16 + lq * 4 + r;
            int col = n0 + wx * 64 + j * 16 + ln15;
            int h = col >> 7, d = col & 127;
            D[(((size_t)b * NHc + h) * SS + s) * HDc + d] = f2bf(acc[i][j][r]);
          }
    }
  } else {
    float* O = (float*)dq;
#pragma unroll
    for (int i = 0; i < 4; ++i)
#pragma unroll
      for (int j = 0; j < 4; ++j)
#pragma unroll
        for (int r = 0; r < 4; ++r) {
          int m = m0 + wy * 64 + i * 16 + lq * 4 + r;
          int n = n0 + wx * 64 + j * 16 + ln15;
          O[(size_t)m * HIDc + n] = acc[i][j][r];
        }
  }
}

// ---------------------------------------------------------------------------
// 4) in-place interleaved RoPE on Q and K
// ---------------------------------------------------------------------------
__global__ void __launch_bounds__(256) rope_kernel(
    unsigned int* __restrict__ Q, unsigned int* __restrict__ Kd,
    const float* __restrict__ cosT, const float* __restrict__ sinT)
{
  constexpr size_t NP = (size_t)BB * NHc * SS * 64;   // pairs per tensor
  size_t gid = (size_t)blockIdx.x * 256 + threadIdx.x;
  unsigned int* P = (gid < NP) ? Q : Kd;
  size_t r = (gid < NP) ? gid : gid - NP;
  int j  = (int)(r & 63);
  int s  = (int)((r >> 6) & (SS - 1));
  int fi = j & 31;
  float c  = cosT[s * 32 + fi];
  float sn = sinT[s * 32 + fi];
  unsigned v = P[r];
  float x1 = bf2f((unsigned short)(v & 0xffff));
  float x2 = bf2f((unsigned short)(v >> 16));
  float y1 = x1 * c - x2 * sn;
  float y2 = x1 * sn + x2 * c;
  P[r] = (unsigned)f2bf(y1) | ((unsigned)f2bf(y2) << 16);
}

// ---------------------------------------------------------------------------
// 5) causal flash attention v2.
//    grid (16, B*NH), 256 thr = 4 waves, each wave owns 32 q-rows.
//    Double-buffered K/V LDS; T14 async-STAGE split (issue loads to regs at
//    loop top, swizzled ds_write after the single per-tile barrier);
//    T13 defer-max; T5 setprio around MFMA clusters.
// ---------------------------------------------------------------------------
__global__ void __launch_bounds__(256) attn_kernel(
    const unsigned short* __restrict__ Qg,
    const unsigned short* __restrict__ Kg,
    const unsigned short* __restrict__ Vg,   // [b][h][d][s]
    unsigned short* __restrict__ Og)
{
  __shared__ __align__(16) unsigned short Klds[2][64 * 128];   // [kv][d] swizzled
  __shared__ __align__(16) unsigned short Vlds[2][128 * 64];   // [d][kv] swizzled
  __shared__ __align__(16) unsigned short Plds[4][32 * 64];    // per-wave
  const int tid = threadIdx.x, lane = tid & 63, w = tid >> 6;
  const int ln15 = lane & 15, lq = lane >> 4;
  const int qt = (int)gridDim.x - 1 - (int)blockIdx.x;  // longest-first dispatch
  const int bh = blockIdx.y;
  const size_t hbase = (size_t)bh * SS * HDc;
  const int q0w = qt * 128 + w * 32;
  const float CE = 1.44269504089f * 0.08838834764831845f;  // log2(e)/sqrt(128)

  short8 aq[2][4];
#pragma unroll
  for (int i = 0; i < 2; ++i)
#pragma unroll
    for (int kf = 0; kf < 4; ++kf)
      aq[i][kf] = *(const short8*)(Qg + hbase + (size_t)(q0w + i * 16 + ln15) * HDc + kf * 32 + lq * 8);

  f32x4 accO[2][8] = {};
  float mr[2][4], lr[2][4];
#pragma unroll
  for (int i = 0; i < 2; ++i)
#pragma unroll
    for (int r = 0; r < 4; ++r) { mr[i][r] = -1e30f; lr[i][r] = 0.f; }

  // staging registers (T14: issue-early / write-late)
  short8 kr[4], vr[4];
  const int krow = tid >> 4, ksl = tid & 15;        // K: [kv 64][d 128]
  const int vd = tid >> 3, vsl = tid & 7;           // V: [d 128][kv 64]
  auto gload = [&](int kv0) {
#pragma unroll
    for (int p = 0; p < 4; ++p) {
      kr[p] = *(const short8*)(Kg + hbase + (size_t)(kv0 + p * 16 + krow) * HDc + ksl * 8);
      vr[p] = *(const short8*)(Vg + hbase + (size_t)(p * 32 + vd) * SS + kv0 + vsl * 8);
    }
  };
  auto swrite = [&](int buf) {
#pragma unroll
    for (int p = 0; p < 4; ++p) {
      int row = p * 16 + krow;
      *(short8*)&Klds[buf][row * 128 + ((ksl ^ (row & 7)) << 3)] = kr[p];
      int d = p * 32 + vd;
      *(short8*)&Vlds[buf][d * 64 + ((vsl ^ (d & 7)) << 3)] = vr[p];
    }
  };

  const int ntiles = 2 * qt + 2;
  gload(0);
  swrite(0);
  int cur = 0;
  for (int kvt = 0; kvt < ntiles; ++kvt) {
    const int kv0 = kvt * 64;
    if (kvt + 1 < ntiles) gload(kv0 + 64);   // issue next tile's loads NOW
    __syncthreads();                         // buf[cur] writes visible

    if (kv0 <= q0w + 31) {
      // S = Q K^T (raw, unscaled)
      f32x4 sf[2][4] = {};
      __builtin_amdgcn_s_setprio(1);
#pragma unroll
      for (int kf = 0; kf < 4; ++kf)
#pragma unroll
        for (int j = 0; j < 4; ++j) {
          int kvrow = j * 16 + ln15;
          short8 bk = *(const short8*)&Klds[cur][kvrow * 128 + (((kf * 4 + lq) ^ (kvrow & 7)) << 3)];
          sf[0][j] = __builtin_amdgcn_mfma_f32_16x16x32_bf16(aq[0][kf], bk, sf[0][j], 0, 0, 0);
          sf[1][j] = __builtin_amdgcn_mfma_f32_16x16x32_bf16(aq[1][kf], bk, sf[1][j], 0, 0, 0);
        }
      __builtin_amdgcn_s_setprio(0);

      if (kv0 + 63 > q0w) {                  // diagonal: causal mask
#pragma unroll
        for (int i = 0; i < 2; ++i)
#pragma unroll
          for (int j = 0; j < 4; ++j)
#pragma unroll
            for (int r = 0; r < 4; ++r) {
              int qr = q0w + i * 16 + lq * 4 + r;
              int kc = kv0 + j * 16 + ln15;
              if (kc > qr) sf[i][j][r] = -1e30f;
            }
      }

      // tile max per (i,r) + defer-max gate (T13)
      float tv[2][4];
      int grow = 0;
#pragma unroll
      for (int i = 0; i < 2; ++i)
#pragma unroll
        for (int r = 0; r < 4; ++r) {
          float v = fmaxf(fmaxf(sf[i][0][r], sf[i][1][r]), fmaxf(sf[i][2][r], sf[i][3][r]));
          v = fmaxf(v, __shfl_xor(v, 1));
          v = fmaxf(v, __shfl_xor(v, 2));
          v = fmaxf(v, __shfl_xor(v, 4));
          v = fmaxf(v, __shfl_xor(v, 8));
          tv[i][r] = v;
          grow |= (CE * (v - mr[i][r]) > 8.0f) ? 1 : 0;
        }
      if (__any(grow)) {
        float al[2][4];
#pragma unroll
        for (int i = 0; i < 2; ++i)
#pragma unroll
          for (int r = 0; r < 4; ++r) {
            float mn = fmaxf(mr[i][r], tv[i][r]);
            al[i][r] = exp2f(CE * (mr[i][r] - mn));
            mr[i][r] = mn;
            lr[i][r] *= al[i][r];
          }
#pragma unroll
        for (int i = 0; i < 2; ++i)
#pragma unroll
          for (int jn = 0; jn < 8; ++jn)
#pragma unroll
            for (int r = 0; r < 4; ++r)
              accO[i][jn][r] *= al[i][r];
      }

      // P = exp2(CE*(s - m)), row sums
#pragma unroll
      for (int i = 0; i < 2; ++i)
#pragma unroll
        for (int r = 0; r < 4; ++r) {
          float sum = 0.f;
#pragma unroll
          for (int j = 0; j < 4; ++j) {
            float p = exp2f(CE * (sf[i][j][r] - mr[i][r]));
            sf[i][j][r] = p;
            sum += p;
          }
          sum += __shfl_xor(sum, 1); sum += __shfl_xor(sum, 2);
          sum += __shfl_xor(sum, 4); sum += __shfl_xor(sum, 8);
          lr[i][r] += sum;
        }

      // P -> per-wave swizzled LDS (bf16)
#pragma unroll
      for (int i = 0; i < 2; ++i)
#pragma unroll
        for (int j = 0; j < 4; ++j)
#pragma unroll
          for (int r = 0; r < 4; ++r) {
            int prow = i * 16 + lq * 4 + r;
            int pcol = j * 16 + ln15;
            Plds[w][prow * 64 + (pcol ^ ((prow & 7) << 3))] = f2bf(sf[i][j][r]);
          }

      // PV
      short8 ap[2][2];
#pragma unroll
      for (int i = 0; i < 2; ++i)
#pragma unroll
        for (int kp = 0; kp < 2; ++kp) {
          int prow = i * 16 + ln15;
          int pcol = kp * 32 + lq * 8;
          ap[i][kp] = *(const short8*)&Plds[w][prow * 64 + (pcol ^ ((prow & 7) << 3))];
        }
      __builtin_amdgcn_s_setprio(1);
#pragma unroll
      for (int jn = 0; jn < 8; ++jn) {
        int d = jn * 16 + ln15;
#pragma unroll
        for (int kp = 0; kp < 2; ++kp) {
          short8 bv = *(const short8*)&Vlds[cur][d * 64 + (((kp * 4 + lq) ^ (d & 7)) << 3)];
          accO[0][jn] = __builtin_amdgcn_mfma_f32_16x16x32_bf16(ap[0][kp], bv, accO[0][jn], 0, 0, 0);
          accO[1][jn] = __builtin_amdgcn_mfma_f32_16x16x32_bf16(ap[1][kp], bv, accO[1][jn], 0, 0, 0);
        }
      }
      __builtin_amdgcn_s_setprio(0);
    }

    if (kvt + 1 < ntiles) swrite(cur ^ 1);   // write-late into other buffer
    cur ^= 1;
  }

  float il[2][4];
#pragma unroll
  for (int i = 0; i < 2; ++i)
#pragma unroll
    for (int r = 0; r < 4; ++r) il[i][r] = 1.0f / lr[i][r];
  const int b = bh >> 4, h = bh & 15;
#pragma unroll
  for (int i = 0; i < 2; ++i)
#pragma unroll
    for (int jn = 0; jn < 8; ++jn)
#pragma unroll
      for (int r = 0; r < 4; ++r) {
        int q = q0w + i * 16 + lq * 4 + r;
        int d = jn * 16 + ln15;
        Og[((size_t)b * SS + q) * HIDc + h * HDc + d] = f2bf(accO[i][jn][r] * il[i][r]);
      }
}

// ---------------------------------------------------------------------------
extern "C" void kernel_launch(void* const* d_in, const int* in_sizes, int n_in,
                              void* d_out, int out_size, void* d_ws, size_t ws_size,
                              hipStream_t stream)
{
  if (ws_size < WS_NEED) return;

  const float* H  = (const float*)d_in[0];
  const float* Wq = (const float*)d_in[1];
  const float* Wk = (const float*)d_in[2];
  const float* Wv = (const float*)d_in[3];
  const float* Wo = (const float*)d_in[4];
  char* ws = (char*)d_ws;
  unsigned short* HB = (unsigned short*)(ws + OFF_HB);
  unsigned short* WB = (unsigned short*)(ws + OFF_WB);
  unsigned short* Qb = (unsigned short*)(ws + OFF_Q);
  unsigned short* Kb = (unsigned short*)(ws + OFF_K);
  unsigned short* Vb = (unsigned short*)(ws + OFF_V);
  unsigned short* AT = (unsigned short*)(ws + OFF_ATT);
  float* cosT = (float*)(ws + OFF_COS);
  float* sinT = (float*)(ws + OFF_SIN);

  cvt_kernel<<<12288, 256, 0, stream>>>(H, Wq, Wk, Wv, Wo, HB);
  rope_tab_kernel<<<256, 256, 0, stream>>>(cosT, sinT);
  gemm_bt<0><<<dim3(16, 32, 3), 256, 0, stream>>>(HB, WB, Qb, Kb, Vb);
  rope_kernel<<<32768, 256, 0, stream>>>((unsigned*)Qb, (unsigned*)Kb, cosT, sinT);
  attn_kernel<<<dim3(16, 32), 256, 0, stream>>>(Qb, Kb, Vb, AT);
  gemm_bt<1><<<dim3(16, 32, 1), 256, 0, stream>>>(AT, WB + (size_t)3 * HIDc * KC,
                                                  d_out, nullptr, nullptr);
}

// Round 3
// 438.866 us; speedup vs baseline: 1.1231x; 1.0998x over previous
//
#include <hip/hip_runtime.h>
#include <math.h>

typedef __attribute__((ext_vector_type(8))) short short8;
typedef __attribute__((ext_vector_type(4))) float f32x4;
typedef __attribute__((ext_vector_type(4))) float fvec4;
typedef __attribute__((ext_vector_type(4))) unsigned short us4;

#define DI __device__ __forceinline__

constexpr int BB = 2, SS = 2048, HIDc = 2048, NHc = 16, HDc = 128;
constexpr int MT = BB * SS;     // 4096 tokens
constexpr int KC = HIDc;        // 2048 inner dim

// ---- workspace layout (bytes) ----
constexpr size_t OFF_HB  = 0;                                      // H bf16   [4096][2048]
constexpr size_t OFF_WB  = OFF_HB + (size_t)MT * KC * 2;           // W bf16   4x[2048][2048]
constexpr size_t OFF_Q   = OFF_WB + (size_t)4 * HIDc * KC * 2;     // Q bf16   [b][h][s][d]
constexpr size_t OFF_K   = OFF_Q  + (size_t)BB * NHc * SS * HDc * 2;
constexpr size_t OFF_V   = OFF_K  + (size_t)BB * NHc * SS * HDc * 2; // V bf16 [b][h][d][s] (transposed!)
constexpr size_t OFF_ATT = OFF_V  + (size_t)BB * NHc * SS * HDc * 2; // attn bf16 [b*s][hid]
constexpr size_t OFF_COS = OFF_ATT + (size_t)MT * HIDc * 2;
constexpr size_t OFF_SIN = OFF_COS + (size_t)SS * 32 * 4;
constexpr size_t WS_NEED = OFF_SIN + (size_t)SS * 32 * 4;          // ~118 MB

DI float bf2f(unsigned short u) { union { unsigned u; float f; } v; v.u = (unsigned)u << 16; return v.f; }
DI unsigned short f2bf(float f) {
  union { float f; unsigned u; } v; v.f = f;
  unsigned r = v.u + 0x7fffu + ((v.u >> 16) & 1u);
  return (unsigned short)(r >> 16);
}

DI void gload_lds16(const void* g, void* l) {
  __builtin_amdgcn_global_load_lds((const __attribute__((address_space(1))) void*)g,
                                   (__attribute__((address_space(3))) void*)l, 16, 0, 0);
}

// ---------------------------------------------------------------------------
// 1) fp32 -> bf16 convert of H and the 4 weights into one contiguous region
// ---------------------------------------------------------------------------
__global__ void __launch_bounds__(256) cvt_kernel(
    const float* __restrict__ H,  const float* __restrict__ W0,
    const float* __restrict__ W1, const float* __restrict__ W2,
    const float* __restrict__ W3, unsigned short* __restrict__ dst)
{
  constexpr size_t HN = (size_t)MT * KC;      // 8388608
  constexpr size_t WN = (size_t)HIDc * KC;    // 4194304 = 2^22
  size_t e0 = ((size_t)blockIdx.x * 256 + threadIdx.x) * 8;
  const float* src; size_t off;
  if (e0 < HN) { src = H; off = e0; }
  else {
    size_t t = e0 - HN; int a = (int)(t >> 22);
    src = (a == 0) ? W0 : (a == 1) ? W1 : (a == 2) ? W2 : W3;
    off = t & (WN - 1);
  }
  fvec4 v0 = *(const fvec4*)(src + off);
  fvec4 v1 = *(const fvec4*)(src + off + 4);
  short8 o;
  o[0] = (short)f2bf(v0[0]); o[1] = (short)f2bf(v0[1]);
  o[2] = (short)f2bf(v0[2]); o[3] = (short)f2bf(v0[3]);
  o[4] = (short)f2bf(v1[0]); o[5] = (short)f2bf(v1[1]);
  o[6] = (short)f2bf(v1[2]); o[7] = (short)f2bf(v1[3]);
  *(short8*)(dst + e0) = o;
}

// ---------------------------------------------------------------------------
// 2) RoPE tables
// ---------------------------------------------------------------------------
__global__ void __launch_bounds__(256) rope_tab_kernel(float* __restrict__ cosT,
                                                       float* __restrict__ sinT)
{
  int idx = blockIdx.x * 256 + threadIdx.x;   // S*32 = 65536
  int t = idx >> 5, fi = idx & 31;
  float inv = powf(10000.0f, -(float)fi * (1.0f / 32.0f));
  float ang = (float)t * inv;
  cosT[idx] = cosf(ang);
  sinT[idx] = sinf(ang);
}

// ---------------------------------------------------------------------------
// 3) bf16 GEMM (m97 structure, 128x128 tile, BK=32, dbuf LDS, global_load_lds)
// ---------------------------------------------------------------------------
template<int EPI>
__global__ void __launch_bounds__(256) gemm_bt(
    const unsigned short* __restrict__ A,
    const unsigned short* __restrict__ Bw,
    void* __restrict__ dq, void* __restrict__ dk, void* __restrict__ dv)
{
  __shared__ __align__(16) unsigned short As[2][128 * 32];
  __shared__ __align__(16) unsigned short Bs[2][128 * 32];
  const int tid = threadIdx.x, lane = tid & 63, w = tid >> 6;
  const int wy = w >> 1, wx = w & 1;
  const int ln15 = lane & 15, lq = lane >> 4;
  const int n0 = blockIdx.x * 128, m0 = blockIdx.y * 128;
  if (EPI == 0) Bw += (size_t)blockIdx.z * HIDc * KC;

  f32x4 acc[4][4] = {};

  auto stage = [&](int kt, int buf) {
#pragma unroll
    for (int p = 0; p < 2; ++p) {
      int c = p * 256 + w * 64 + lane;           // 16B chunk id within tile
      int row = c >> 2, k0 = (c & 3) << 3;
      const unsigned short* ga = A  + (size_t)(m0 + row) * KC + kt * 32 + k0;
      const unsigned short* gb = Bw + (size_t)(n0 + row) * KC + kt * 32 + k0;
      unsigned short* la = &As[buf][(p * 256 + w * 64) * 8];  // wave-uniform base
      unsigned short* lb = &Bs[buf][(p * 256 + w * 64) * 8];
      gload_lds16(ga, la);
      gload_lds16(gb, lb);
    }
  };

  stage(0, 0);
  __syncthreads();
  constexpr int KT = KC / 32;
  for (int kt = 0; kt < KT; ++kt) {
    int cur = kt & 1;
    if (kt + 1 < KT) stage(kt + 1, cur ^ 1);
    short8 af[4], bfr[4];
#pragma unroll
    for (int i = 0; i < 4; ++i)
      af[i] = *(const short8*)&As[cur][(wy * 64 + i * 16 + ln15) * 32 + lq * 8];
#pragma unroll
    for (int j = 0; j < 4; ++j)
      bfr[j] = *(const short8*)&Bs[cur][(wx * 64 + j * 16 + ln15) * 32 + lq * 8];
#pragma unroll
    for (int i = 0; i < 4; ++i)
#pragma unroll
      for (int j = 0; j < 4; ++j)
        acc[i][j] = __builtin_amdgcn_mfma_f32_16x16x32_bf16(af[i], bfr[j], acc[i][j], 0, 0, 0);
    __syncthreads();
  }

  if (EPI == 0) {
    const int z = blockIdx.z;
    const int b = m0 >> 11;
    const int srow = m0 & 2047;
    if (z == 2) {
      unsigned short* V = (unsigned short*)dv;
#pragma unroll
      for (int i = 0; i < 4; ++i)
#pragma unroll
        for (int j = 0; j < 4; ++j) {
          int s0 = srow + wy * 64 + i * 16 + lq * 4;
          int col = n0 + wx * 64 + j * 16 + ln15;
          int h = col >> 7, d = col & 127;
          size_t ad = (((size_t)b * NHc + h) * HDc + d) * SS + s0;
          us4 pk;
#pragma unroll
          for (int r = 0; r < 4; ++r) pk[r] = f2bf(acc[i][j][r]);
          *(us4*)((unsigned short*)V + ad) = pk;
        }
    } else {
      unsigned short* D = (unsigned short*)(z ? dk : dq);
#pragma unroll
      for (int i = 0; i < 4; ++i)
#pragma unroll
        for (int j = 0; j < 4; ++j)
#pragma unroll
          for (int r = 0; r < 4; ++r) {
            int s = srow + wy * 64 + i * 16 + lq * 4 + r;
            int col = n0 + wx * 64 + j * 16 + ln15;
            int h = col >> 7, d = col & 127;
            D[(((size_t)b * NHc + h) * SS + s) * HDc + d] = f2bf(acc[i][j][r]);
          }
    }
  } else {
    float* O = (float*)dq;
#pragma unroll
    for (int i = 0; i < 4; ++i)
#pragma unroll
      for (int j = 0; j < 4; ++j)
#pragma unroll
        for (int r = 0; r < 4; ++r) {
          int m = m0 + wy * 64 + i * 16 + lq * 4 + r;
          int n = n0 + wx * 64 + j * 16 + ln15;
          O[(size_t)m * HIDc + n] = acc[i][j][r];
        }
  }
}

// ---------------------------------------------------------------------------
// 4) in-place interleaved RoPE on Q and K
// ---------------------------------------------------------------------------
__global__ void __launch_bounds__(256) rope_kernel(
    unsigned int* __restrict__ Q, unsigned int* __restrict__ Kd,
    const float* __restrict__ cosT, const float* __restrict__ sinT)
{
  constexpr size_t NP = (size_t)BB * NHc * SS * 64;   // pairs per tensor
  size_t gid = (size_t)blockIdx.x * 256 + threadIdx.x;
  unsigned int* P = (gid < NP) ? Q : Kd;
  size_t r = (gid < NP) ? gid : gid - NP;
  int j  = (int)(r & 63);
  int s  = (int)((r >> 6) & (SS - 1));
  int fi = j & 31;
  float c  = cosT[s * 32 + fi];
  float sn = sinT[s * 32 + fi];
  unsigned v = P[r];
  float x1 = bf2f((unsigned short)(v & 0xffff));
  float x2 = bf2f((unsigned short)(v >> 16));
  float y1 = x1 * c - x2 * sn;
  float y2 = x1 * sn + x2 * c;
  P[r] = (unsigned)f2bf(y1) | ((unsigned)f2bf(y2) << 16);
}

// ---------------------------------------------------------------------------
// 5) causal flash attention v3.
//    512 blocks, 4 waves each. Mirror-pair load balancing: waves 0,1 own
//    64-row q-tile t; waves 2,3 own q-tile 31-t -> uniform 66 wave-tiles of
//    compute per block. KV staged by global_load_lds (16B) with PRE-SWIZZLED
//    global source + linear LDS dest, double-buffered, one barrier/tile.
//    XCD-aware block decode (bh%8 == wg%8) for KV L2 locality.
// ---------------------------------------------------------------------------
__global__ void __launch_bounds__(256) attn_kernel(
    const unsigned short* __restrict__ Qg,
    const unsigned short* __restrict__ Kg,
    const unsigned short* __restrict__ Vg,   // [b][h][d][s]
    unsigned short* __restrict__ Og)
{
  __shared__ __align__(16) unsigned short Klds[2][64 * 128];   // [kv][d] swizzled
  __shared__ __align__(16) unsigned short Vlds[2][128 * 64];   // [d][kv] swizzled
  __shared__ __align__(16) unsigned short Plds[4][32 * 64];    // per-wave
  const int tid = threadIdx.x, lane = tid & 63, w = tid >> 6;
  const int ln15 = lane & 15, lq = lane >> 4;

  // XCD-aware decode: 512 blocks -> (t 0..15, bh 0..31) with bh%8 == wg%8
  const int wg = blockIdx.x;
  const int xcd = wg & 7, idx = wg >> 3;     // idx 0..63
  const int bh = xcd + 8 * (idx & 3);        // bh%8 == xcd
  const int t  = idx >> 2;                   // 0..15 (pair id)

  const int qtile = (w < 2) ? t : (31 - t);  // this wave's 64-row q-tile
  const int q0w = qtile * 64 + (w & 1) * 32; // this wave's 32 q-rows
  const int ntiles = 32 - t;                 // KV tiles staged (covers high tile)

  const size_t hbase = (size_t)bh * SS * HDc;
  const float CE = 1.44269504089f * 0.08838834764831845f;  // log2(e)/sqrt(128)

  short8 aq[2][4];
#pragma unroll
  for (int i = 0; i < 2; ++i)
#pragma unroll
    for (int kf = 0; kf < 4; ++kf)
      aq[i][kf] = *(const short8*)(Qg + hbase + (size_t)(q0w + i * 16 + ln15) * HDc + kf * 32 + lq * 8);

  f32x4 accO[2][8] = {};
  float mr[2][4], lr[2][4];
#pragma unroll
  for (int i = 0; i < 2; ++i)
#pragma unroll
    for (int r = 0; r < 4; ++r) { mr[i][r] = -1e30f; lr[i][r] = 0.f; }

  // direct global->LDS staging; swizzle folded into the GLOBAL source address,
  // LDS destination stays linear (wave-uniform base + lane*16).
  auto stage = [&](int kvt, int buf) {
    const int kv0 = kvt * 64;
#pragma unroll
    for (int p = 0; p < 4; ++p) {
      int c = p * 256 + w * 64 + lane;       // 16B chunk id, 1024 per tile
      int krow = c >> 4, ksl = c & 15;       // K: [kv 64][d 128]
      gload_lds16(Kg + hbase + (size_t)(kv0 + krow) * HDc + ((ksl ^ (krow & 7)) << 3),
                  (unsigned short*)&Klds[buf][0] + (size_t)(p * 256 + w * 64) * 8);
      int vd = c >> 3, vsl = c & 7;          // V: [d 128][kv 64]
      gload_lds16(Vg + hbase + (size_t)vd * SS + kv0 + ((vsl ^ (vd & 7)) << 3),
                  (unsigned short*)&Vlds[buf][0] + (size_t)(p * 256 + w * 64) * 8);
    }
  };

  stage(0, 0);
  __syncthreads();
  int cur = 0;
  for (int kvt = 0; kvt < ntiles; ++kvt) {
    if (kvt + 1 < ntiles) stage(kvt + 1, cur ^ 1);   // async into other buffer

    if (kvt <= qtile) {
      const int kv0 = kvt * 64;
      // S = Q K^T (raw, unscaled)
      f32x4 sf[2][4] = {};
      __builtin_amdgcn_s_setprio(1);
#pragma unroll
      for (int kf = 0; kf < 4; ++kf)
#pragma unroll
        for (int j = 0; j < 4; ++j) {
          int kvrow = j * 16 + ln15;
          short8 bk = *(const short8*)&Klds[cur][kvrow * 128 + (((kf * 4 + lq) ^ (kvrow & 7)) << 3)];
          sf[0][j] = __builtin_amdgcn_mfma_f32_16x16x32_bf16(aq[0][kf], bk, sf[0][j], 0, 0, 0);
          sf[1][j] = __builtin_amdgcn_mfma_f32_16x16x32_bf16(aq[1][kf], bk, sf[1][j], 0, 0, 0);
        }
      __builtin_amdgcn_s_setprio(0);

      if (kvt == qtile) {                    // diagonal: causal mask
#pragma unroll
        for (int i = 0; i < 2; ++i)
#pragma unroll
          for (int j = 0; j < 4; ++j)
#pragma unroll
            for (int r = 0; r < 4; ++r) {
              int qr = q0w + i * 16 + lq * 4 + r;
              int kc = kv0 + j * 16 + ln15;
              if (kc > qr) sf[i][j][r] = -1e30f;
            }
      }

      // tile max per (i,r) + defer-max gate (T13)
      float tv[2][4];
      int grow = 0;
#pragma unroll
      for (int i = 0; i < 2; ++i)
#pragma unroll
        for (int r = 0; r < 4; ++r) {
          float v = fmaxf(fmaxf(sf[i][0][r], sf[i][1][r]), fmaxf(sf[i][2][r], sf[i][3][r]));
          v = fmaxf(v, __shfl_xor(v, 1));
          v = fmaxf(v, __shfl_xor(v, 2));
          v = fmaxf(v, __shfl_xor(v, 4));
          v = fmaxf(v, __shfl_xor(v, 8));
          tv[i][r] = v;
          grow |= (CE * (v - mr[i][r]) > 8.0f) ? 1 : 0;
        }
      if (__any(grow)) {
        float al[2][4];
#pragma unroll
        for (int i = 0; i < 2; ++i)
#pragma unroll
          for (int r = 0; r < 4; ++r) {
            float mn = fmaxf(mr[i][r], tv[i][r]);
            al[i][r] = exp2f(CE * (mr[i][r] - mn));
            mr[i][r] = mn;
            lr[i][r] *= al[i][r];
          }
#pragma unroll
        for (int i = 0; i < 2; ++i)
#pragma unroll
          for (int jn = 0; jn < 8; ++jn)
#pragma unroll
            for (int r = 0; r < 4; ++r)
              accO[i][jn][r] *= al[i][r];
      }

      // P = exp2(CE*(s - m)), row sums
#pragma unroll
      for (int i = 0; i < 2; ++i)
#pragma unroll
        for (int r = 0; r < 4; ++r) {
          float sum = 0.f;
#pragma unroll
          for (int j = 0; j < 4; ++j) {
            float p = exp2f(CE * (sf[i][j][r] - mr[i][r]));
            sf[i][j][r] = p;
            sum += p;
          }
          sum += __shfl_xor(sum, 1); sum += __shfl_xor(sum, 2);
          sum += __shfl_xor(sum, 4); sum += __shfl_xor(sum, 8);
          lr[i][r] += sum;
        }

      // P -> per-wave swizzled LDS (bf16)
#pragma unroll
      for (int i = 0; i < 2; ++i)
#pragma unroll
        for (int j = 0; j < 4; ++j)
#pragma unroll
          for (int r = 0; r < 4; ++r) {
            int prow = i * 16 + lq * 4 + r;
            int pcol = j * 16 + ln15;
            Plds[w][prow * 64 + (pcol ^ ((prow & 7) << 3))] = f2bf(sf[i][j][r]);
          }

      // PV
      short8 ap[2][2];
#pragma unroll
      for (int i = 0; i < 2; ++i)
#pragma unroll
        for (int kp = 0; kp < 2; ++kp) {
          int prow = i * 16 + ln15;
          int pcol = kp * 32 + lq * 8;
          ap[i][kp] = *(const short8*)&Plds[w][prow * 64 + (pcol ^ ((prow & 7) << 3))];
        }
      __builtin_amdgcn_s_setprio(1);
#pragma unroll
      for (int jn = 0; jn < 8; ++jn) {
        int d = jn * 16 + ln15;
#pragma unroll
        for (int kp = 0; kp < 2; ++kp) {
          short8 bv = *(const short8*)&Vlds[cur][d * 64 + (((kp * 4 + lq) ^ (d & 7)) << 3)];
          accO[0][jn] = __builtin_amdgcn_mfma_f32_16x16x32_bf16(ap[0][kp], bv, accO[0][jn], 0, 0, 0);
          accO[1][jn] = __builtin_amdgcn_mfma_f32_16x16x32_bf16(ap[1][kp], bv, accO[1][jn], 0, 0, 0);
        }
      }
      __builtin_amdgcn_s_setprio(0);
    }

    __syncthreads();   // compiler drains vmcnt here -> buf[cur^1] complete
    cur ^= 1;
  }

  float il[2][4];
#pragma unroll
  for (int i = 0; i < 2; ++i)
#pragma unroll
    for (int r = 0; r < 4; ++r) il[i][r] = 1.0f / lr[i][r];
  const int b = bh >> 4, h = bh & 15;
#pragma unroll
  for (int i = 0; i < 2; ++i)
#pragma unroll
    for (int jn = 0; jn < 8; ++jn)
#pragma unroll
      for (int r = 0; r < 4; ++r) {
        int q = q0w + i * 16 + lq * 4 + r;
        int d = jn * 16 + ln15;
        Og[((size_t)b * SS + q) * HIDc + h * HDc + d] = f2bf(accO[i][jn][r] * il[i][r]);
      }
}

// ---------------------------------------------------------------------------
extern "C" void kernel_launch(void* const* d_in, const int* in_sizes, int n_in,
                              void* d_out, int out_size, void* d_ws, size_t ws_size,
                              hipStream_t stream)
{
  if (ws_size < WS_NEED) return;

  const float* H  = (const float*)d_in[0];
  const float* Wq = (const float*)d_in[1];
  const float* Wk = (const float*)d_in[2];
  const float* Wv = (const float*)d_in[3];
  const float* Wo = (const float*)d_in[4];
  char* ws = (char*)d_ws;
  unsigned short* HB = (unsigned short*)(ws + OFF_HB);
  unsigned short* WB = (unsigned short*)(ws + OFF_WB);
  unsigned short* Qb = (unsigned short*)(ws + OFF_Q);
  unsigned short* Kb = (unsigned short*)(ws + OFF_K);
  unsigned short* Vb = (unsigned short*)(ws + OFF_V);
  unsigned short* AT = (unsigned short*)(ws + OFF_ATT);
  float* cosT = (float*)(ws + OFF_COS);
  float* sinT = (float*)(ws + OFF_SIN);

  cvt_kernel<<<12288, 256, 0, stream>>>(H, Wq, Wk, Wv, Wo, HB);
  rope_tab_kernel<<<256, 256, 0, stream>>>(cosT, sinT);
  gemm_bt<0><<<dim3(16, 32, 3), 256, 0, stream>>>(HB, WB, Qb, Kb, Vb);
  rope_kernel<<<32768, 256, 0, stream>>>((unsigned*)Qb, (unsigned*)Kb, cosT, sinT);
  attn_kernel<<<512, 256, 0, stream>>>(Qb, Kb, Vb, AT);
  gemm_bt<1><<<dim3(16, 32, 1), 256, 0, stream>>>(AT, WB + (size_t)3 * HIDc * KC,
                                                  d_out, nullptr, nullptr);
}

// Round 6
// 386.186 us; speedup vs baseline: 1.2763x; 1.1364x over previous
//
#include <hip/hip_runtime.h>
#include <math.h>

typedef __attribute__((ext_vector_type(8))) short short8;
typedef __attribute__((ext_vector_type(4))) float f32x4;
typedef __attribute__((ext_vector_type(16))) float f32x16;
typedef __attribute__((ext_vector_type(4))) float fvec4;
typedef __attribute__((ext_vector_type(4))) unsigned short us4;

#define DI __device__ __forceinline__

constexpr int BB = 2, SS = 2048, HIDc = 2048, NHc = 16, HDc = 128;
constexpr int MT = BB * SS;     // 4096 tokens
constexpr int KC = HIDc;        // 2048 inner dim

// ---- workspace layout (bytes) ----
constexpr size_t OFF_HB  = 0;                                      // H bf16   [4096][2048]
constexpr size_t OFF_WB  = OFF_HB + (size_t)MT * KC * 2;           // W bf16   4x[2048][2048]
constexpr size_t OFF_Q   = OFF_WB + (size_t)4 * HIDc * KC * 2;     // Q bf16   [b][h][s][d]
constexpr size_t OFF_K   = OFF_Q  + (size_t)BB * NHc * SS * HDc * 2;
constexpr size_t OFF_V   = OFF_K  + (size_t)BB * NHc * SS * HDc * 2; // V bf16 [b][h][d][s] (transposed!)
constexpr size_t OFF_ATT = OFF_V  + (size_t)BB * NHc * SS * HDc * 2; // attn bf16 [b*s][hid]
constexpr size_t OFF_COS = OFF_ATT + (size_t)MT * HIDc * 2;
constexpr size_t OFF_SIN = OFF_COS + (size_t)SS * 32 * 4;
constexpr size_t WS_NEED = OFF_SIN + (size_t)SS * 32 * 4;          // ~118 MB

DI float bf2f(unsigned short u) { union { unsigned u; float f; } v; v.u = (unsigned)u << 16; return v.f; }
DI unsigned short f2bf(float f) {
  union { float f; unsigned u; } v; v.f = f;
  unsigned r = v.u + 0x7fffu + ((v.u >> 16) & 1u);
  return (unsigned short)(r >> 16);
}

DI void gload_lds16(const void* g, void* l) {
  __builtin_amdgcn_global_load_lds((const __attribute__((address_space(1))) void*)g,
                                   (__attribute__((address_space(3))) void*)l, 16, 0, 0);
}

DI unsigned cvtpk_bf16(float lo, float hi_) {
  unsigned r;
  asm("v_cvt_pk_bf16_f32 %0, %1, %2" : "=v"(r) : "v"(lo), "v"(hi_));
  return r;
}

// ---------------------------------------------------------------------------
// 1) fp32 -> bf16 convert of H and the 4 weights into one contiguous region
// ---------------------------------------------------------------------------
__global__ void __launch_bounds__(256) cvt_kernel(
    const float* __restrict__ H,  const float* __restrict__ W0,
    const float* __restrict__ W1, const float* __restrict__ W2,
    const float* __restrict__ W3, unsigned short* __restrict__ dst)
{
  constexpr size_t HN = (size_t)MT * KC;      // 8388608
  constexpr size_t WN = (size_t)HIDc * KC;    // 4194304 = 2^22
  size_t e0 = ((size_t)blockIdx.x * 256 + threadIdx.x) * 8;
  const float* src; size_t off;
  if (e0 < HN) { src = H; off = e0; }
  else {
    size_t t = e0 - HN; int a = (int)(t >> 22);
    src = (a == 0) ? W0 : (a == 1) ? W1 : (a == 2) ? W2 : W3;
    off = t & (WN - 1);
  }
  fvec4 v0 = *(const fvec4*)(src + off);
  fvec4 v1 = *(const fvec4*)(src + off + 4);
  short8 o;
  o[0] = (short)f2bf(v0[0]); o[1] = (short)f2bf(v0[1]);
  o[2] = (short)f2bf(v0[2]); o[3] = (short)f2bf(v0[3]);
  o[4] = (short)f2bf(v1[0]); o[5] = (short)f2bf(v1[1]);
  o[6] = (short)f2bf(v1[2]); o[7] = (short)f2bf(v1[3]);
  *(short8*)(dst + e0) = o;
}

// ---------------------------------------------------------------------------
// 2) RoPE tables
// ---------------------------------------------------------------------------
__global__ void __launch_bounds__(256) rope_tab_kernel(float* __restrict__ cosT,
                                                       float* __restrict__ sinT)
{
  int idx = blockIdx.x * 256 + threadIdx.x;   // S*32 = 65536
  int t = idx >> 5, fi = idx & 31;
  float inv = powf(10000.0f, -(float)fi * (1.0f / 32.0f));
  float ang = (float)t * inv;
  cosT[idx] = cosf(ang);
  sinT[idx] = sinf(ang);
}

// ---------------------------------------------------------------------------
// 3) bf16 GEMM (m97 structure, 128x128 tile, BK=32, dbuf LDS, global_load_lds)
// ---------------------------------------------------------------------------
template<int EPI>
__global__ void __launch_bounds__(256) gemm_bt(
    const unsigned short* __restrict__ A,
    const unsigned short* __restrict__ Bw,
    void* __restrict__ dq, void* __restrict__ dk, void* __restrict__ dv)
{
  __shared__ __align__(16) unsigned short As[2][128 * 32];
  __shared__ __align__(16) unsigned short Bs[2][128 * 32];
  const int tid = threadIdx.x, lane = tid & 63, w = tid >> 6;
  const int wy = w >> 1, wx = w & 1;
  const int ln15 = lane & 15, lq = lane >> 4;
  const int n0 = blockIdx.x * 128, m0 = blockIdx.y * 128;
  if (EPI == 0) Bw += (size_t)blockIdx.z * HIDc * KC;

  f32x4 acc[4][4] = {};

  auto stage = [&](int kt, int buf) {
#pragma unroll
    for (int p = 0; p < 2; ++p) {
      int c = p * 256 + w * 64 + lane;           // 16B chunk id within tile
      int row = c >> 2, k0 = (c & 3) << 3;
      const unsigned short* ga = A  + (size_t)(m0 + row) * KC + kt * 32 + k0;
      const unsigned short* gb = Bw + (size_t)(n0 + row) * KC + kt * 32 + k0;
      unsigned short* la = &As[buf][(p * 256 + w * 64) * 8];  // wave-uniform base
      unsigned short* lb = &Bs[buf][(p * 256 + w * 64) * 8];
      gload_lds16(ga, la);
      gload_lds16(gb, lb);
    }
  };

  stage(0, 0);
  __syncthreads();
  constexpr int KT = KC / 32;
  for (int kt = 0; kt < KT; ++kt) {
    int cur = kt & 1;
    if (kt + 1 < KT) stage(kt + 1, cur ^ 1);
    short8 af[4], bfr[4];
#pragma unroll
    for (int i = 0; i < 4; ++i)
      af[i] = *(const short8*)&As[cur][(wy * 64 + i * 16 + ln15) * 32 + lq * 8];
#pragma unroll
    for (int j = 0; j < 4; ++j)
      bfr[j] = *(const short8*)&Bs[cur][(wx * 64 + j * 16 + ln15) * 32 + lq * 8];
#pragma unroll
    for (int i = 0; i < 4; ++i)
#pragma unroll
      for (int j = 0; j < 4; ++j)
        acc[i][j] = __builtin_amdgcn_mfma_f32_16x16x32_bf16(af[i], bfr[j], acc[i][j], 0, 0, 0);
    __syncthreads();
  }

  if (EPI == 0) {
    const int z = blockIdx.z;
    const int b = m0 >> 11;
    const int srow = m0 & 2047;
    if (z == 2) {
      unsigned short* V = (unsigned short*)dv;
#pragma unroll
      for (int i = 0; i < 4; ++i)
#pragma unroll
        for (int j = 0; j < 4; ++j) {
          int s0 = srow + wy * 64 + i * 16 + lq * 4;
          int col = n0 + wx * 64 + j * 16 + ln15;
          int h = col >> 7, d = col & 127;
          size_t ad = (((size_t)b * NHc + h) * HDc + d) * SS + s0;
          us4 pk;
#pragma unroll
          for (int r = 0; r < 4; ++r) pk[r] = f2bf(acc[i][j][r]);
          *(us4*)((unsigned short*)V + ad) = pk;
        }
    } else {
      unsigned short* D = (unsigned short*)(z ? dk : dq);
#pragma unroll
      for (int i = 0; i < 4; ++i)
#pragma unroll
        for (int j = 0; j < 4; ++j)
#pragma unroll
          for (int r = 0; r < 4; ++r) {
            int s = srow + wy * 64 + i * 16 + lq * 4 + r;
            int col = n0 + wx * 64 + j * 16 + ln15;
            int h = col >> 7, d = col & 127;
            D[(((size_t)b * NHc + h) * SS + s) * HDc + d] = f2bf(acc[i][j][r]);
          }
    }
  } else {
    float* O = (float*)dq;
#pragma unroll
    for (int i = 0; i < 4; ++i)
#pragma unroll
      for (int j = 0; j < 4; ++j)
#pragma unroll
        for (int r = 0; r < 4; ++r) {
          int m = m0 + wy * 64 + i * 16 + lq * 4 + r;
          int n = n0 + wx * 64 + j * 16 + ln15;
          O[(size_t)m * HIDc + n] = acc[i][j][r];
        }
  }
}

// ---------------------------------------------------------------------------
// 4) in-place interleaved RoPE on Q and K
// ---------------------------------------------------------------------------
__global__ void __launch_bounds__(256) rope_kernel(
    unsigned int* __restrict__ Q, unsigned int* __restrict__ Kd,
    const float* __restrict__ cosT, const float* __restrict__ sinT)
{
  constexpr size_t NP = (size_t)BB * NHc * SS * 64;   // pairs per tensor
  size_t gid = (size_t)blockIdx.x * 256 + threadIdx.x;
  unsigned int* P = (gid < NP) ? Q : Kd;
  size_t r = (gid < NP) ? gid : gid - NP;
  int j  = (int)(r & 63);
  int s  = (int)((r >> 6) & (SS - 1));
  int fi = j & 31;
  float c  = cosT[s * 32 + fi];
  float sn = sinT[s * 32 + fi];
  unsigned v = P[r];
  float x1 = bf2f((unsigned short)(v & 0xffff));
  float x2 = bf2f((unsigned short)(v >> 16));
  float y1 = x1 * c - x2 * sn;
  float y2 = x1 * sn + x2 * c;
  P[r] = (unsigned)f2bf(y1) | ((unsigned)f2bf(y2) << 16);
}

// ---------------------------------------------------------------------------
// 5) causal flash attention v6 — swapped-QK 32x32, in-register softmax,
//    P routed through small per-wave swizzled LDS so the PV A-operand uses
//    the SAME memory placement as the V-load (sigma-proof; only relies on
//    the HW-verified C/D layout + sigma_A == sigma_B).
//    512 blocks, 4 waves; waves 0,1: 64-row q-tile t, waves 2,3: tile 31-t.
// ---------------------------------------------------------------------------
__global__ void __launch_bounds__(256) attn_kernel(
    const unsigned short* __restrict__ Qg,
    const unsigned short* __restrict__ Kg,
    const unsigned short* __restrict__ Vg,   // [b][h][d][s]
    unsigned short* __restrict__ Og)
{
  __shared__ __align__(16) unsigned short Klds[2][64 * 128];   // [kv][d] swizzled
  __shared__ __align__(16) unsigned short Vlds[2][128 * 64];   // [d][kv] swizzled
  __shared__ __align__(16) unsigned short Plds[4][32 * 64];    // per-wave [q][kv] swizzled
  const int tid = threadIdx.x, lane = tid & 63, w = tid >> 6;
  const int l31 = lane & 31, hi = lane >> 5;

  // XCD-aware decode: 512 blocks -> (t 0..15, bh 0..31) with bh%8 == wg%8
  const int wg = blockIdx.x;
  const int xcd = wg & 7, idx = wg >> 3;
  const int bh = xcd + 8 * (idx & 3);
  const int t  = idx >> 2;                   // 0..15 (pair id)

  const int qtile = (w < 2) ? t : (31 - t);  // 64-row tile
  const int sub1 = w & 1;                    // which 32-row half (wave-uniform)
  const int q0w = qtile * 64 + sub1 * 32;
  const int ntiles = 32 - t;

  const size_t hbase = (size_t)bh * SS * HDc;
  const float CE = 1.44269504089f * 0.08838834764831845f;  // log2(e)/sqrt(128)

  // Q fragments: lane -> q-row (q0w + l31), 8 k-steps of 16 d each
  short8 qf[8];
#pragma unroll
  for (int ks = 0; ks < 8; ++ks)
    qf[ks] = *(const short8*)(Qg + hbase + (size_t)(q0w + l31) * HDc + ks * 16 + hi * 8);

  f32x16 accO[4];
#pragma unroll
  for (int db = 0; db < 4; ++db)
#pragma unroll
    for (int r = 0; r < 16; ++r) accO[db][r] = 0.f;
  float mr = -1e30f, lr = 0.f;

  auto stage = [&](int kvt, int buf) {
    const int kv0 = kvt * 64;
#pragma unroll
    for (int p = 0; p < 4; ++p) {
      int c = p * 256 + w * 64 + lane;       // 16B chunk id, 1024 per tile
      int krow = c >> 4, ksl = c & 15;       // K: [kv 64][d 128]
      gload_lds16(Kg + hbase + (size_t)(kv0 + krow) * HDc + ((ksl ^ (krow & 7)) << 3),
                  (unsigned short*)&Klds[buf][0] + (size_t)(p * 256 + w * 64) * 8);
      int vd = c >> 3, vsl = c & 7;          // V: [d 128][kv 64]
      gload_lds16(Vg + hbase + (size_t)vd * SS + kv0 + ((vsl ^ (vd & 7)) << 3),
                  (unsigned short*)&Vlds[buf][0] + (size_t)(p * 256 + w * 64) * 8);
    }
  };

  stage(0, 0);
  __syncthreads();
  int cur = 0;
  for (int kvt = 0; kvt < ntiles; ++kvt) {
    if (kvt + 1 < ntiles) stage(kvt + 1, cur ^ 1);

    if (kvt <= qtile) {
      const bool diag = (kvt == qtile);
      const bool haveT1 = (!diag) || sub1;   // wave-uniform

      // ---- swapped QK^T: D[k][q], A = K rows, B = Q ----
      f32x16 s0, s1;
#pragma unroll
      for (int r = 0; r < 16; ++r) s0[r] = 0.f;
      __builtin_amdgcn_s_setprio(1);
#pragma unroll
      for (int ks = 0; ks < 8; ++ks) {
        int row = l31;                       // kv-half 0
        short8 kf = *(const short8*)&Klds[cur][row * 128 + (((2 * ks + hi) ^ (row & 7)) << 3)];
        s0 = __builtin_amdgcn_mfma_f32_32x32x16_bf16(kf, qf[ks], s0, 0, 0, 0);
      }
      if (haveT1) {
#pragma unroll
        for (int r = 0; r < 16; ++r) s1[r] = 0.f;
#pragma unroll
        for (int ks = 0; ks < 8; ++ks) {
          int row = 32 + l31;                // kv-half 1
          short8 kf = *(const short8*)&Klds[cur][row * 128 + (((2 * ks + hi) ^ (row & 7)) << 3)];
          s1 = __builtin_amdgcn_mfma_f32_32x32x16_bf16(kf, qf[ks], s1, 0, 0, 0);
        }
      }
      __builtin_amdgcn_s_setprio(0);

      if (diag) {                            // mask rowid > own q within 32-block
        if (sub1) {
#pragma unroll
          for (int r = 0; r < 16; ++r)
            if (((r & 3) + 8 * (r >> 2) + 4 * hi) > l31) s1[r] = -1e30f;
        } else {
#pragma unroll
          for (int r = 0; r < 16; ++r)
            if (((r & 3) + 8 * (r >> 2) + 4 * hi) > l31) s0[r] = -1e30f;
        }
      }

      // ---- in-register online softmax (lane owns q = q0w + l31) ----
      float pmax = s0[0];
#pragma unroll
      for (int r = 1; r < 16; ++r) pmax = fmaxf(pmax, s0[r]);
      if (haveT1) {
#pragma unroll
        for (int r = 0; r < 16; ++r) pmax = fmaxf(pmax, s1[r]);
      }
      pmax = fmaxf(pmax, __shfl_xor(pmax, 32));      // cross-half combine

      int grow = (CE * (pmax - mr) > 8.0f) ? 1 : 0;  // T13 defer-max
      if (__any(grow)) {
        float mn = fmaxf(mr, pmax);
        float al = exp2f(CE * (mr - mn));
        mr = mn; lr *= al;
        float alr[16];
#pragma unroll
        for (int r = 0; r < 16; ++r)
          alr[r] = __shfl(al, (r & 3) + 8 * (r >> 2) + 4 * hi);
#pragma unroll
        for (int db = 0; db < 4; ++db)
#pragma unroll
          for (int r = 0; r < 16; ++r) accO[db][r] *= alr[r];
      }

      float psum = 0.f;
#pragma unroll
      for (int r = 0; r < 16; ++r) {
        float p = exp2f(CE * (s0[r] - mr));
        s0[r] = p; psum += p;
      }
      if (haveT1) {
#pragma unroll
        for (int r = 0; r < 16; ++r) {
          float p = exp2f(CE * (s1[r] - mr));
          s1[r] = p; psum += p;
        }
      }
      psum += __shfl_xor(psum, 32);                  // cross-half combine
      lr += psum;

      // ---- P -> per-wave LDS [q=l31][kv], chunk-XOR swizzled, bf16 pairs ----
      // register r holds kv = (r&3) + 8*(r>>2) + 4*hi; pairs (2i,2i+1) are
      // kv = (i&1)*2 + (i>>1)*8 + 4*hi (+0/+32 for s0/s1), kv+1.
#pragma unroll
      for (int i = 0; i < 8; ++i) {
        int kv = (i & 1) * 2 + (i >> 1) * 8 + 4 * hi;
        unsigned pk = cvtpk_bf16(s0[2 * i], s0[2 * i + 1]);
        *(unsigned*)&Plds[w][l31 * 64 + (((kv >> 3) ^ (l31 & 7)) << 3) + (kv & 7)] = pk;
      }
      if (haveT1) {
#pragma unroll
        for (int i = 0; i < 8; ++i) {
          int kv = 32 + (i & 1) * 2 + (i >> 1) * 8 + 4 * hi;
          unsigned pk = cvtpk_bf16(s1[2 * i], s1[2 * i + 1]);
          *(unsigned*)&Plds[w][l31 * 64 + (((kv >> 3) ^ (l31 & 7)) << 3) + (kv & 7)] = pk;
        }
      }

      // ---- PV: D[q][d] += P[q][k] V[k][d]; A read with SAME placement as V ----
      short8 ap[4];
#pragma unroll
      for (int ks = 0; ks < 2; ++ks)
        ap[ks] = *(const short8*)&Plds[w][l31 * 64 + (((2 * ks + hi) ^ (l31 & 7)) << 3)];
      if (haveT1) {
#pragma unroll
        for (int ks = 2; ks < 4; ++ks)
          ap[ks] = *(const short8*)&Plds[w][l31 * 64 + (((2 * ks + hi) ^ (l31 & 7)) << 3)];
      }

      __builtin_amdgcn_s_setprio(1);
#pragma unroll
      for (int db = 0; db < 4; ++db) {
        int row = db * 32 + l31;             // V^T row = d
#pragma unroll
        for (int ks = 0; ks < 2; ++ks) {
          short8 vf = *(const short8*)&Vlds[cur][row * 64 + (((2 * ks + hi) ^ (row & 7)) << 3)];
          accO[db] = __builtin_amdgcn_mfma_f32_32x32x16_bf16(ap[ks], vf, accO[db], 0, 0, 0);
        }
      }
      if (haveT1) {
#pragma unroll
        for (int db = 0; db < 4; ++db) {
          int row = db * 32 + l31;
#pragma unroll
          for (int ks = 2; ks < 4; ++ks) {
            short8 vf = *(const short8*)&Vlds[cur][row * 64 + (((2 * ks + hi) ^ (row & 7)) << 3)];
            accO[db] = __builtin_amdgcn_mfma_f32_32x32x16_bf16(ap[ks], vf, accO[db], 0, 0, 0);
          }
        }
      }
      __builtin_amdgcn_s_setprio(0);
    }

    __syncthreads();   // drains vmcnt -> buf[cur^1] ready
    cur ^= 1;
  }

  // ---- epilogue: O[q][d] = accO / lr ----
  float il = 1.0f / lr;
  float ilr[16];
#pragma unroll
  for (int r = 0; r < 16; ++r)
    ilr[r] = __shfl(il, (r & 3) + 8 * (r >> 2) + 4 * hi);
  const int b = bh >> 4, h = bh & 15;
#pragma unroll
  for (int db = 0; db < 4; ++db)
#pragma unroll
    for (int r = 0; r < 16; ++r) {
      int q = q0w + (r & 3) + 8 * (r >> 2) + 4 * hi;
      int d = db * 32 + l31;
      Og[((size_t)b * SS + q) * HIDc + h * HDc + d] = f2bf(accO[db][r] * ilr[r]);
    }
}

// ---------------------------------------------------------------------------
extern "C" void kernel_launch(void* const* d_in, const int* in_sizes, int n_in,
                              void* d_out, int out_size, void* d_ws, size_t ws_size,
                              hipStream_t stream)
{
  if (ws_size < WS_NEED) return;

  const float* H  = (const float*)d_in[0];
  const float* Wq = (const float*)d_in[1];
  const float* Wk = (const float*)d_in[2];
  const float* Wv = (const float*)d_in[3];
  const float* Wo = (const float*)d_in[4];
  char* ws = (char*)d_ws;
  unsigned short* HB = (unsigned short*)(ws + OFF_HB);
  unsigned short* WB = (unsigned short*)(ws + OFF_WB);
  unsigned short* Qb = (unsigned short*)(ws + OFF_Q);
  unsigned short* Kb = (unsigned short*)(ws + OFF_K);
  unsigned short* Vb = (unsigned short*)(ws + OFF_V);
  unsigned short* AT = (unsigned short*)(ws + OFF_ATT);
  float* cosT = (float*)(ws + OFF_COS);
  float* sinT = (float*)(ws + OFF_SIN);

  cvt_kernel<<<12288, 256, 0, stream>>>(H, Wq, Wk, Wv, Wo, HB);
  rope_tab_kernel<<<256, 256, 0, stream>>>(cosT, sinT);
  gemm_bt<0><<<dim3(16, 32, 3), 256, 0, stream>>>(HB, WB, Qb, Kb, Vb);
  rope_kernel<<<32768, 256, 0, stream>>>((unsigned*)Qb, (unsigned*)Kb, cosT, sinT);
  attn_kernel<<<512, 256, 0, stream>>>(Qb, Kb, Vb, AT);
  gemm_bt<1><<<dim3(16, 32, 1), 256, 0, stream>>>(AT, WB + (size_t)3 * HIDc * KC,
                                                  d_out, nullptr, nullptr);
}

// Round 7
// 353.568 us; speedup vs baseline: 1.3940x; 1.0923x over previous
//
#include <hip/hip_runtime.h>
#include <math.h>

typedef __attribute__((ext_vector_type(8))) short short8;
typedef __attribute__((ext_vector_type(4))) float f32x4;
typedef __attribute__((ext_vector_type(16))) float f32x16;
typedef __attribute__((ext_vector_type(4))) float fvec4;
typedef __attribute__((ext_vector_type(4))) unsigned short us4;

#define DI __device__ __forceinline__
#define BARX asm volatile("s_barrier" ::: "memory")
#define WAITV6 asm volatile("s_waitcnt vmcnt(6)" ::: "memory")
#define WAITV0 asm volatile("s_waitcnt vmcnt(0)" ::: "memory")
#define SCHED0 __builtin_amdgcn_sched_barrier(0)

constexpr int BB = 2, SS = 2048, HIDc = 2048, NHc = 16, HDc = 128;
constexpr int MT = BB * SS;     // 4096 tokens
constexpr int KC = HIDc;        // 2048 inner dim

// ---- workspace layout (bytes) ----
constexpr size_t OFF_HB  = 0;                                      // H bf16   [4096][2048]
constexpr size_t OFF_WB  = OFF_HB + (size_t)MT * KC * 2;           // W bf16   4x[2048][2048]
constexpr size_t OFF_Q   = OFF_WB + (size_t)4 * HIDc * KC * 2;     // Q bf16   [b][h][s][d]
constexpr size_t OFF_K   = OFF_Q  + (size_t)BB * NHc * SS * HDc * 2;
constexpr size_t OFF_V   = OFF_K  + (size_t)BB * NHc * SS * HDc * 2; // V bf16 [b][h][d][s]
constexpr size_t OFF_ATT = OFF_V  + (size_t)BB * NHc * SS * HDc * 2; // attn bf16 [b*s][hid]
constexpr size_t OFF_COS = OFF_ATT + (size_t)MT * HIDc * 2;
constexpr size_t OFF_SIN = OFF_COS + (size_t)SS * 32 * 4;
constexpr size_t WS_NEED = OFF_SIN + (size_t)SS * 32 * 4;          // ~118 MB

DI float bf2f(unsigned short u) { union { unsigned u; float f; } v; v.u = (unsigned)u << 16; return v.f; }
DI unsigned short f2bf(float f) {
  union { float f; unsigned u; } v; v.f = f;
  unsigned r = v.u + 0x7fffu + ((v.u >> 16) & 1u);
  return (unsigned short)(r >> 16);
}

DI void gload_lds16(const void* g, void* l) {
  __builtin_amdgcn_global_load_lds((const __attribute__((address_space(1))) void*)g,
                                   (__attribute__((address_space(3))) void*)l, 16, 0, 0);
}

DI unsigned cvtpk_bf16(float lo, float hi_) {
  unsigned r;
  asm("v_cvt_pk_bf16_f32 %0, %1, %2" : "=v"(r) : "v"(lo), "v"(hi_));
  return r;
}

// ---------------------------------------------------------------------------
// 1) fp32 -> bf16 convert of H and the 4 weights into one contiguous region
// ---------------------------------------------------------------------------
__global__ void __launch_bounds__(256) cvt_kernel(
    const float* __restrict__ H,  const float* __restrict__ W0,
    const float* __restrict__ W1, const float* __restrict__ W2,
    const float* __restrict__ W3, unsigned short* __restrict__ dst)
{
  constexpr size_t HN = (size_t)MT * KC;      // 8388608
  constexpr size_t WN = (size_t)HIDc * KC;    // 4194304 = 2^22
  size_t e0 = ((size_t)blockIdx.x * 256 + threadIdx.x) * 8;
  const float* src; size_t off;
  if (e0 < HN) { src = H; off = e0; }
  else {
    size_t t = e0 - HN; int a = (int)(t >> 22);
    src = (a == 0) ? W0 : (a == 1) ? W1 : (a == 2) ? W2 : W3;
    off = t & (WN - 1);
  }
  fvec4 v0 = *(const fvec4*)(src + off);
  fvec4 v1 = *(const fvec4*)(src + off + 4);
  short8 o;
  o[0] = (short)f2bf(v0[0]); o[1] = (short)f2bf(v0[1]);
  o[2] = (short)f2bf(v0[2]); o[3] = (short)f2bf(v0[3]);
  o[4] = (short)f2bf(v1[0]); o[5] = (short)f2bf(v1[1]);
  o[6] = (short)f2bf(v1[2]); o[7] = (short)f2bf(v1[3]);
  *(short8*)(dst + e0) = o;
}

// ---------------------------------------------------------------------------
// 2) RoPE tables
// ---------------------------------------------------------------------------
__global__ void __launch_bounds__(256) rope_tab_kernel(float* __restrict__ cosT,
                                                       float* __restrict__ sinT)
{
  int idx = blockIdx.x * 256 + threadIdx.x;   // S*32 = 65536
  int t = idx >> 5, fi = idx & 31;
  float inv = powf(10000.0f, -(float)fi * (1.0f / 32.0f));
  float ang = (float)t * inv;
  cosT[idx] = cosf(ang);
  sinT[idx] = sinf(ang);
}

// ---------------------------------------------------------------------------
// 3) Pipelined bf16 GEMM: C[m][n] = sum_k A[m][k] B[n][k].
//    BM=256, BN=128, BK=64, 512 thr (8 waves, 4m x 2n, per-wave 64x64).
//    3-deep circular LDS (144 KiB), prefetch distance 2, counted vmcnt(6),
//    4 phases/K-tile {ds_read quadrant | gload_lds stage | barrier | MFMA}.
//    Swizzle: 16B-chunk position = chunk ^ (row&7), both sides (involution).
//    EPI 0: QKV epilogue over folded N=6144 (z = col>>11: Q,K [b][h][s][d];
//           V [b][h][d][s]).  EPI 1: fp32 row-major out.
// ---------------------------------------------------------------------------
template<int EPI, int NBX>
__global__ void __launch_bounds__(512, 2) gemm8(
    const unsigned short* __restrict__ A,
    const unsigned short* __restrict__ Bw,
    void* __restrict__ dq, void* __restrict__ dk, void* __restrict__ dv)
{
  __shared__ __align__(16) unsigned short Al[3][256 * 64];
  __shared__ __align__(16) unsigned short Bl[3][128 * 64];
  const int tid = threadIdx.x, lane = tid & 63, w = tid >> 6;
  const int wm = w >> 1, wn = w & 1;
  const int ln15 = lane & 15, lq = lane >> 4;

  // XCD-chunked decode: 16 by-tiles, NBX bx-tiles, 8 XCDs -> by = xcd*2 + ...
  const int xcd = blockIdx.x & 7, idx = blockIdx.x >> 3;
  const int by = xcd * 2 + idx / NBX, bx = idx % NBX;
  const int m0 = by * 256, n0 = bx * 128;

  // staging thread constants: chunk q = l*512 + tid; row = q>>3, slotpos = q&7,
  // source chunk c = slot ^ (row&7)  (involution with the read swizzle)
  const int srow = tid >> 3;                 // 0..63
  const int sc = (tid & 7) ^ (srow & 7);
  const unsigned short* asrc[4];
  const unsigned short* bsrc[2];
#pragma unroll
  for (int l = 0; l < 4; ++l) asrc[l] = A  + (size_t)(m0 + l * 64 + srow) * KC + sc * 8;
#pragma unroll
  for (int l = 0; l < 2; ++l) bsrc[l] = Bw + (size_t)(n0 + l * 64 + srow) * KC + sc * 8;

  // frag read offsets (ushort units): row*64 + slot*8, slot = (kk*4+lq)^(ln15&7)
  const int x7 = ln15 & 7;
  const int slA0 = (lq ^ x7) * 8;
  const int slA1 = ((4 + lq) ^ x7) * 8;
  int rA[4], rB[4];
#pragma unroll
  for (int i = 0; i < 4; ++i) rA[i] = (wm * 64 + i * 16 + ln15) * 64;
#pragma unroll
  for (int j = 0; j < 4; ++j) rB[j] = (wn * 64 + j * 16 + ln15) * 64;

  constexpr int NT = KC / 64;   // 32
  auto stA = [&](int kt, int buf, int l) {
    gload_lds16(asrc[l] + (size_t)kt * 64, &Al[buf][(size_t)(l * 512 + w * 64) * 8]);
  };
  auto stB = [&](int kt, int buf, int l) {
    gload_lds16(bsrc[l] + (size_t)kt * 64, &Bl[buf][(size_t)(l * 512 + w * 64) * 8]);
  };

  // prologue: stage tiles 0,1 (6 loads each); wait tile0; barrier
  stA(0, 0, 0); stA(0, 0, 1); stA(0, 0, 2); stA(0, 0, 3); stB(0, 0, 0); stB(0, 0, 1);
  stA(1, 1, 0); stA(1, 1, 1); stA(1, 1, 2); stA(1, 1, 3); stB(1, 1, 0); stB(1, 1, 1);
  WAITV6; BARX;

  f32x4 acc[4][4] = {};
  int cb = 0, nb = 2;
  for (int kt = 0; kt < NT; ++kt) {
    const unsigned short* Ac = &Al[cb][0];
    const unsigned short* Bc = &Bl[cb][0];
    const bool pf = (kt + 2 < NT);
    short8 a01[2][2], a23[2][2], b01[2][2], b23[2][2];

    // ---- phase 0: read A(m0,m1)+B(n0,n1), stage A-halves 0,1 of kt+2 ----
#pragma unroll
    for (int i = 0; i < 2; ++i) {
      a01[i][0] = *(const short8*)&Ac[rA[i] + slA0];
      a01[i][1] = *(const short8*)&Ac[rA[i] + slA1];
      b01[i][0] = *(const short8*)&Bc[rB[i] + slA0];
      b01[i][1] = *(const short8*)&Bc[rB[i] + slA1];
    }
    if (pf) { stA(kt + 2, nb, 0); stA(kt + 2, nb, 1); }
    BARX; SCHED0;
    __builtin_amdgcn_s_setprio(1);
#pragma unroll
    for (int i = 0; i < 2; ++i)
#pragma unroll
      for (int j = 0; j < 2; ++j)
#pragma unroll
        for (int k = 0; k < 2; ++k)
          acc[i][j] = __builtin_amdgcn_mfma_f32_16x16x32_bf16(a01[i][k], b01[j][k], acc[i][j], 0, 0, 0);
    __builtin_amdgcn_s_setprio(0);
    BARX;

    // ---- phase 1: read B(n2,n3), stage A-halves 2,3 ----
#pragma unroll
    for (int j = 0; j < 2; ++j) {
      b23[j][0] = *(const short8*)&Bc[rB[2 + j] + slA0];
      b23[j][1] = *(const short8*)&Bc[rB[2 + j] + slA1];
    }
    if (pf) { stA(kt + 2, nb, 2); stA(kt + 2, nb, 3); }
    BARX; SCHED0;
    __builtin_amdgcn_s_setprio(1);
#pragma unroll
    for (int i = 0; i < 2; ++i)
#pragma unroll
      for (int j = 0; j < 2; ++j)
#pragma unroll
        for (int k = 0; k < 2; ++k)
          acc[i][2 + j] = __builtin_amdgcn_mfma_f32_16x16x32_bf16(a01[i][k], b23[j][k], acc[i][2 + j], 0, 0, 0);
    __builtin_amdgcn_s_setprio(0);
    BARX;

    // ---- phase 2: read A(m2,m3), stage B-half 0 ----
#pragma unroll
    for (int i = 0; i < 2; ++i) {
      a23[i][0] = *(const short8*)&Ac[rA[2 + i] + slA0];
      a23[i][1] = *(const short8*)&Ac[rA[2 + i] + slA1];
    }
    if (pf) stB(kt + 2, nb, 0);
    BARX; SCHED0;
    __builtin_amdgcn_s_setprio(1);
#pragma unroll
    for (int i = 0; i < 2; ++i)
#pragma unroll
      for (int j = 0; j < 2; ++j)
#pragma unroll
        for (int k = 0; k < 2; ++k)
          acc[2 + i][2 + j] = __builtin_amdgcn_mfma_f32_16x16x32_bf16(a23[i][k], b23[j][k], acc[2 + i][2 + j], 0, 0, 0);
    __builtin_amdgcn_s_setprio(0);
    BARX;

    // ---- phase 3: stage B-half 1, MFMA, counted vmcnt, barrier ----
    if (pf) stB(kt + 2, nb, 1);
    SCHED0;
    __builtin_amdgcn_s_setprio(1);
#pragma unroll
    for (int i = 0; i < 2; ++i)
#pragma unroll
      for (int j = 0; j < 2; ++j)
#pragma unroll
        for (int k = 0; k < 2; ++k)
          acc[2 + i][j] = __builtin_amdgcn_mfma_f32_16x16x32_bf16(a23[i][k], b01[j][k], acc[2 + i][j], 0, 0, 0);
    __builtin_amdgcn_s_setprio(0);
    if (kt < NT - 2) { WAITV6; }
    else if (kt == NT - 2) { WAITV0; }
    BARX;

    cb = (cb == 2) ? 0 : cb + 1;
    nb = (nb == 2) ? 0 : nb + 1;
  }

  // ---- epilogue ----
  if (EPI == 0) {
#pragma unroll
    for (int i = 0; i < 4; ++i)
#pragma unroll
      for (int j = 0; j < 4; ++j) {
        int colb = n0 + wn * 64 + j * 16;         // + ln15
        int z = colb >> 11;
        int c2 = (colb & 2047) + ln15;
        int h = c2 >> 7, d = c2 & 127;
        int m = m0 + wm * 64 + i * 16 + lq * 4;   // + rr
        int b = m >> 11, s = m & 2047;
        if (z == 2) {
          us4 pk;
#pragma unroll
          for (int r = 0; r < 4; ++r) pk[r] = f2bf(acc[i][j][r]);
          *(us4*)((unsigned short*)dv + (((size_t)b * NHc + h) * HDc + d) * SS + s) = pk;
        } else {
          unsigned short* D = (unsigned short*)(z ? dk : dq);
#pragma unroll
          for (int r = 0; r < 4; ++r)
            D[(((size_t)b * NHc + h) * SS + s + r) * HDc + d] = f2bf(acc[i][j][r]);
        }
      }
  } else {
    float* O = (float*)dq;
#pragma unroll
    for (int i = 0; i < 4; ++i)
#pragma unroll
      for (int j = 0; j < 4; ++j) {
        int col = n0 + wn * 64 + j * 16 + ln15;
        int m = m0 + wm * 64 + i * 16 + lq * 4;
#pragma unroll
        for (int r = 0; r < 4; ++r)
          O[(size_t)(m + r) * HIDc + col] = acc[i][j][r];
      }
  }
}

// ---------------------------------------------------------------------------
// 4) in-place interleaved RoPE on Q and K
// ---------------------------------------------------------------------------
__global__ void __launch_bounds__(256) rope_kernel(
    unsigned int* __restrict__ Q, unsigned int* __restrict__ Kd,
    const float* __restrict__ cosT, const float* __restrict__ sinT)
{
  constexpr size_t NP = (size_t)BB * NHc * SS * 64;   // pairs per tensor
  size_t gid = (size_t)blockIdx.x * 256 + threadIdx.x;
  unsigned int* P = (gid < NP) ? Q : Kd;
  size_t r = (gid < NP) ? gid : gid - NP;
  int j  = (int)(r & 63);
  int s  = (int)((r >> 6) & (SS - 1));
  int fi = j & 31;
  float c  = cosT[s * 32 + fi];
  float sn = sinT[s * 32 + fi];
  unsigned v = P[r];
  float x1 = bf2f((unsigned short)(v & 0xffff));
  float x2 = bf2f((unsigned short)(v >> 16));
  float y1 = x1 * c - x2 * sn;
  float y2 = x1 * sn + x2 * c;
  P[r] = (unsigned)f2bf(y1) | ((unsigned)f2bf(y2) << 16);
}

// ---------------------------------------------------------------------------
// 5) causal flash attention (v6 structure, unchanged)
// ---------------------------------------------------------------------------
__global__ void __launch_bounds__(256) attn_kernel(
    const unsigned short* __restrict__ Qg,
    const unsigned short* __restrict__ Kg,
    const unsigned short* __restrict__ Vg,   // [b][h][d][s]
    unsigned short* __restrict__ Og)
{
  __shared__ __align__(16) unsigned short Klds[2][64 * 128];   // [kv][d] swizzled
  __shared__ __align__(16) unsigned short Vlds[2][128 * 64];   // [d][kv] swizzled
  __shared__ __align__(16) unsigned short Plds[4][32 * 64];    // per-wave [q][kv] swizzled
  const int tid = threadIdx.x, lane = tid & 63, w = tid >> 6;
  const int l31 = lane & 31, hi = lane >> 5;

  const int wg = blockIdx.x;
  const int xcd = wg & 7, idx = wg >> 3;
  const int bh = xcd + 8 * (idx & 3);
  const int t  = idx >> 2;                   // 0..15 (pair id)

  const int qtile = (w < 2) ? t : (31 - t);
  const int sub1 = w & 1;
  const int q0w = qtile * 64 + sub1 * 32;
  const int ntiles = 32 - t;

  const size_t hbase = (size_t)bh * SS * HDc;
  const float CE = 1.44269504089f * 0.08838834764831845f;  // log2(e)/sqrt(128)

  short8 qf[8];
#pragma unroll
  for (int ks = 0; ks < 8; ++ks)
    qf[ks] = *(const short8*)(Qg + hbase + (size_t)(q0w + l31) * HDc + ks * 16 + hi * 8);

  f32x16 accO[4];
#pragma unroll
  for (int db = 0; db < 4; ++db)
#pragma unroll
    for (int r = 0; r < 16; ++r) accO[db][r] = 0.f;
  float mr = -1e30f, lr = 0.f;

  auto stage = [&](int kvt, int buf) {
    const int kv0 = kvt * 64;
#pragma unroll
    for (int p = 0; p < 4; ++p) {
      int c = p * 256 + w * 64 + lane;
      int krow = c >> 4, ksl = c & 15;
      gload_lds16(Kg + hbase + (size_t)(kv0 + krow) * HDc + ((ksl ^ (krow & 7)) << 3),
                  (unsigned short*)&Klds[buf][0] + (size_t)(p * 256 + w * 64) * 8);
      int vd = c >> 3, vsl = c & 7;
      gload_lds16(Vg + hbase + (size_t)vd * SS + kv0 + ((vsl ^ (vd & 7)) << 3),
                  (unsigned short*)&Vlds[buf][0] + (size_t)(p * 256 + w * 64) * 8);
    }
  };

  stage(0, 0);
  __syncthreads();
  int cur = 0;
  for (int kvt = 0; kvt < ntiles; ++kvt) {
    if (kvt + 1 < ntiles) stage(kvt + 1, cur ^ 1);

    if (kvt <= qtile) {
      const bool diag = (kvt == qtile);
      const bool haveT1 = (!diag) || sub1;

      f32x16 s0, s1;
#pragma unroll
      for (int r = 0; r < 16; ++r) s0[r] = 0.f;
      __builtin_amdgcn_s_setprio(1);
#pragma unroll
      for (int ks = 0; ks < 8; ++ks) {
        int row = l31;
        short8 kf = *(const short8*)&Klds[cur][row * 128 + (((2 * ks + hi) ^ (row & 7)) << 3)];
        s0 = __builtin_amdgcn_mfma_f32_32x32x16_bf16(kf, qf[ks], s0, 0, 0, 0);
      }
      if (haveT1) {
#pragma unroll
        for (int r = 0; r < 16; ++r) s1[r] = 0.f;
#pragma unroll
        for (int ks = 0; ks < 8; ++ks) {
          int row = 32 + l31;
          short8 kf = *(const short8*)&Klds[cur][row * 128 + (((2 * ks + hi) ^ (row & 7)) << 3)];
          s1 = __builtin_amdgcn_mfma_f32_32x32x16_bf16(kf, qf[ks], s1, 0, 0, 0);
        }
      }
      __builtin_amdgcn_s_setprio(0);

      if (diag) {
        if (sub1) {
#pragma unroll
          for (int r = 0; r < 16; ++r)
            if (((r & 3) + 8 * (r >> 2) + 4 * hi) > l31) s1[r] = -1e30f;
        } else {
#pragma unroll
          for (int r = 0; r < 16; ++r)
            if (((r & 3) + 8 * (r >> 2) + 4 * hi) > l31) s0[r] = -1e30f;
        }
      }

      float pmax = s0[0];
#pragma unroll
      for (int r = 1; r < 16; ++r) pmax = fmaxf(pmax, s0[r]);
      if (haveT1) {
#pragma unroll
        for (int r = 0; r < 16; ++r) pmax = fmaxf(pmax, s1[r]);
      }
      pmax = fmaxf(pmax, __shfl_xor(pmax, 32));

      int grow = (CE * (pmax - mr) > 8.0f) ? 1 : 0;
      if (__any(grow)) {
        float mn = fmaxf(mr, pmax);
        float al = exp2f(CE * (mr - mn));
        mr = mn; lr *= al;
        float alr[16];
#pragma unroll
        for (int r = 0; r < 16; ++r)
          alr[r] = __shfl(al, (r & 3) + 8 * (r >> 2) + 4 * hi);
#pragma unroll
        for (int db = 0; db < 4; ++db)
#pragma unroll
          for (int r = 0; r < 16; ++r) accO[db][r] *= alr[r];
      }

      float psum = 0.f;
#pragma unroll
      for (int r = 0; r < 16; ++r) {
        float p = exp2f(CE * (s0[r] - mr));
        s0[r] = p; psum += p;
      }
      if (haveT1) {
#pragma unroll
        for (int r = 0; r < 16; ++r) {
          float p = exp2f(CE * (s1[r] - mr));
          s1[r] = p; psum += p;
        }
      }
      psum += __shfl_xor(psum, 32);
      lr += psum;

#pragma unroll
      for (int i = 0; i < 8; ++i) {
        int kv = (i & 1) * 2 + (i >> 1) * 8 + 4 * hi;
        unsigned pk = cvtpk_bf16(s0[2 * i], s0[2 * i + 1]);
        *(unsigned*)&Plds[w][l31 * 64 + (((kv >> 3) ^ (l31 & 7)) << 3) + (kv & 7)] = pk;
      }
      if (haveT1) {
#pragma unroll
        for (int i = 0; i < 8; ++i) {
          int kv = 32 + (i & 1) * 2 + (i >> 1) * 8 + 4 * hi;
          unsigned pk = cvtpk_bf16(s1[2 * i], s1[2 * i + 1]);
          *(unsigned*)&Plds[w][l31 * 64 + (((kv >> 3) ^ (l31 & 7)) << 3) + (kv & 7)] = pk;
        }
      }

      short8 ap[4];
#pragma unroll
      for (int ks = 0; ks < 2; ++ks)
        ap[ks] = *(const short8*)&Plds[w][l31 * 64 + (((2 * ks + hi) ^ (l31 & 7)) << 3)];
      if (haveT1) {
#pragma unroll
        for (int ks = 2; ks < 4; ++ks)
          ap[ks] = *(const short8*)&Plds[w][l31 * 64 + (((2 * ks + hi) ^ (l31 & 7)) << 3)];
      }

      __builtin_amdgcn_s_setprio(1);
#pragma unroll
      for (int db = 0; db < 4; ++db) {
        int row = db * 32 + l31;
#pragma unroll
        for (int ks = 0; ks < 2; ++ks) {
          short8 vf = *(const short8*)&Vlds[cur][row * 64 + (((2 * ks + hi) ^ (row & 7)) << 3)];
          accO[db] = __builtin_amdgcn_mfma_f32_32x32x16_bf16(ap[ks], vf, accO[db], 0, 0, 0);
        }
      }
      if (haveT1) {
#pragma unroll
        for (int db = 0; db < 4; ++db) {
          int row = db * 32 + l31;
#pragma unroll
          for (int ks = 2; ks < 4; ++ks) {
            short8 vf = *(const short8*)&Vlds[cur][row * 64 + (((2 * ks + hi) ^ (row & 7)) << 3)];
            accO[db] = __builtin_amdgcn_mfma_f32_32x32x16_bf16(ap[ks], vf, accO[db], 0, 0, 0);
          }
        }
      }
      __builtin_amdgcn_s_setprio(0);
    }

    __syncthreads();
    cur ^= 1;
  }

  float il = 1.0f / lr;
  float ilr[16];
#pragma unroll
  for (int r = 0; r < 16; ++r)
    ilr[r] = __shfl(il, (r & 3) + 8 * (r >> 2) + 4 * hi);
  const int b = bh >> 4, h = bh & 15;
#pragma unroll
  for (int db = 0; db < 4; ++db)
#pragma unroll
    for (int r = 0; r < 16; ++r) {
      int q = q0w + (r & 3) + 8 * (r >> 2) + 4 * hi;
      int d = db * 32 + l31;
      Og[((size_t)b * SS + q) * HIDc + h * HDc + d] = f2bf(accO[db][r] * ilr[r]);
    }
}

// ---------------------------------------------------------------------------
extern "C" void kernel_launch(void* const* d_in, const int* in_sizes, int n_in,
                              void* d_out, int out_size, void* d_ws, size_t ws_size,
                              hipStream_t stream)
{
  if (ws_size < WS_NEED) return;

  const float* H  = (const float*)d_in[0];
  const float* Wq = (const float*)d_in[1];
  const float* Wk = (const float*)d_in[2];
  const float* Wv = (const float*)d_in[3];
  const float* Wo = (const float*)d_in[4];
  char* ws = (char*)d_ws;
  unsigned short* HB = (unsigned short*)(ws + OFF_HB);
  unsigned short* WB = (unsigned short*)(ws + OFF_WB);
  unsigned short* Qb = (unsigned short*)(ws + OFF_Q);
  unsigned short* Kb = (unsigned short*)(ws + OFF_K);
  unsigned short* Vb = (unsigned short*)(ws + OFF_V);
  unsigned short* AT = (unsigned short*)(ws + OFF_ATT);
  float* cosT = (float*)(ws + OFF_COS);
  float* sinT = (float*)(ws + OFF_SIN);

  cvt_kernel<<<12288, 256, 0, stream>>>(H, Wq, Wk, Wv, Wo, HB);
  rope_tab_kernel<<<256, 256, 0, stream>>>(cosT, sinT);
  // QKV: folded N = 6144 (WB = [Wq;Wk;Wv]) -> grid 8 XCD * 2 by * 48 bx = 768
  gemm8<0, 48><<<768, 512, 0, stream>>>(HB, WB, Qb, Kb, Vb);
  rope_kernel<<<32768, 256, 0, stream>>>((unsigned*)Qb, (unsigned*)Kb, cosT, sinT);
  attn_kernel<<<512, 256, 0, stream>>>(Qb, Kb, Vb, AT);
  // proj: N = 2048 -> grid 8 * 2 * 16 = 256
  gemm8<1, 16><<<256, 512, 0, stream>>>(AT, WB + (size_t)3 * HIDc * KC,
                                        d_out, nullptr, nullptr);
}

// Round 8
// 320.468 us; speedup vs baseline: 1.5380x; 1.1033x over previous
//
#include <hip/hip_runtime.h>
#include <math.h>

typedef __attribute__((ext_vector_type(8))) short short8;
typedef __attribute__((ext_vector_type(4))) float f32x4;
typedef __attribute__((ext_vector_type(16))) float f32x16;
typedef __attribute__((ext_vector_type(4))) float fvec4;
typedef __attribute__((ext_vector_type(4))) unsigned short us4;

#define DI __device__ __forceinline__
#define BARX asm volatile("s_barrier" ::: "memory")
#define WAITV6 asm volatile("s_waitcnt vmcnt(6)" ::: "memory")
#define WAITV0 asm volatile("s_waitcnt vmcnt(0)" ::: "memory")
#define WAITL0 asm volatile("s_waitcnt lgkmcnt(0)" ::: "memory")
#define SCHED0 __builtin_amdgcn_sched_barrier(0)

constexpr int BB = 2, SS = 2048, HIDc = 2048, NHc = 16, HDc = 128;
constexpr int MT = BB * SS;     // 4096 tokens
constexpr int KC = HIDc;        // 2048 inner dim

// ---- workspace layout (bytes) ----
constexpr size_t OFF_HB  = 0;                                      // H bf16   [4096][2048]
constexpr size_t OFF_WB  = OFF_HB + (size_t)MT * KC * 2;           // W bf16   4x[2048][2048]
constexpr size_t OFF_Q   = OFF_WB + (size_t)4 * HIDc * KC * 2;     // Q bf16   [b][h][s][d]
constexpr size_t OFF_K   = OFF_Q  + (size_t)BB * NHc * SS * HDc * 2;
constexpr size_t OFF_V   = OFF_K  + (size_t)BB * NHc * SS * HDc * 2; // V bf16 [b][h][d][s]
constexpr size_t OFF_ATT = OFF_V  + (size_t)BB * NHc * SS * HDc * 2; // attn bf16 [b*s][hid]
constexpr size_t OFF_COS = OFF_ATT + (size_t)MT * HIDc * 2;
constexpr size_t OFF_SIN = OFF_COS + (size_t)SS * 32 * 4;
constexpr size_t WS_NEED = OFF_SIN + (size_t)SS * 32 * 4;          // ~118 MB

DI float bf2f(unsigned short u) { union { unsigned u; float f; } v; v.u = (unsigned)u << 16; return v.f; }
DI unsigned short f2bf(float f) {
  union { float f; unsigned u; } v; v.f = f;
  unsigned r = v.u + 0x7fffu + ((v.u >> 16) & 1u);
  return (unsigned short)(r >> 16);
}

DI void gload_lds16(const void* g, void* l) {
  __builtin_amdgcn_global_load_lds((const __attribute__((address_space(1))) void*)g,
                                   (__attribute__((address_space(3))) void*)l, 16, 0, 0);
}

DI unsigned cvtpk_bf16(float lo, float hi_) {
  unsigned r;
  asm("v_cvt_pk_bf16_f32 %0, %1, %2" : "=v"(r) : "v"(lo), "v"(hi_));
  return r;
}

// ---------------------------------------------------------------------------
// 1) fp32 -> bf16 convert of H and the 4 weights into one contiguous region
// ---------------------------------------------------------------------------
__global__ void __launch_bounds__(256) cvt_kernel(
    const float* __restrict__ H,  const float* __restrict__ W0,
    const float* __restrict__ W1, const float* __restrict__ W2,
    const float* __restrict__ W3, unsigned short* __restrict__ dst)
{
  constexpr size_t HN = (size_t)MT * KC;      // 8388608
  constexpr size_t WN = (size_t)HIDc * KC;    // 4194304 = 2^22
  size_t e0 = ((size_t)blockIdx.x * 256 + threadIdx.x) * 8;
  const float* src; size_t off;
  if (e0 < HN) { src = H; off = e0; }
  else {
    size_t t = e0 - HN; int a = (int)(t >> 22);
    src = (a == 0) ? W0 : (a == 1) ? W1 : (a == 2) ? W2 : W3;
    off = t & (WN - 1);
  }
  fvec4 v0 = *(const fvec4*)(src + off);
  fvec4 v1 = *(const fvec4*)(src + off + 4);
  short8 o;
  o[0] = (short)f2bf(v0[0]); o[1] = (short)f2bf(v0[1]);
  o[2] = (short)f2bf(v0[2]); o[3] = (short)f2bf(v0[3]);
  o[4] = (short)f2bf(v1[0]); o[5] = (short)f2bf(v1[1]);
  o[6] = (short)f2bf(v1[2]); o[7] = (short)f2bf(v1[3]);
  *(short8*)(dst + e0) = o;
}

// ---------------------------------------------------------------------------
// 2) RoPE tables
// ---------------------------------------------------------------------------
__global__ void __launch_bounds__(256) rope_tab_kernel(float* __restrict__ cosT,
                                                       float* __restrict__ sinT)
{
  int idx = blockIdx.x * 256 + threadIdx.x;   // S*32 = 65536
  int t = idx >> 5, fi = idx & 31;
  float inv = powf(10000.0f, -(float)fi * (1.0f / 32.0f));
  float ang = (float)t * inv;
  cosT[idx] = cosf(ang);
  sinT[idx] = sinf(ang);
}

// ---------------------------------------------------------------------------
// 3) Pipelined bf16 GEMM: C[m][n] = sum_k A[m][k] B[n][k].
//    BM=256, BN=128, BK=64, 512 thr (8 waves, 4m x 2n, per-wave 64x64).
//    3-deep circular LDS (144 KiB), prefetch distance 2, counted vmcnt(6),
//    2 phases/K-tile, 16-MFMA clusters between barrier pairs.
//    Swizzle: 16B-chunk position = chunk ^ (row&7), both sides (involution).
// ---------------------------------------------------------------------------
template<int EPI, int NBX>
__global__ void __launch_bounds__(512, 2) gemm8(
    const unsigned short* __restrict__ A,
    const unsigned short* __restrict__ Bw,
    void* __restrict__ dq, void* __restrict__ dk, void* __restrict__ dv)
{
  __shared__ __align__(16) unsigned short Al[3][256 * 64];
  __shared__ __align__(16) unsigned short Bl[3][128 * 64];
  const int tid = threadIdx.x, lane = tid & 63, w = tid >> 6;
  const int wm = w >> 1, wn = w & 1;
  const int ln15 = lane & 15, lq = lane >> 4;

  const int xcd = blockIdx.x & 7, idx = blockIdx.x >> 3;
  const int by = xcd * 2 + idx / NBX, bx = idx % NBX;
  const int m0 = by * 256, n0 = bx * 128;

  const int srow = tid >> 3;                 // 0..63
  const int sc = (tid & 7) ^ (srow & 7);
  const unsigned short* asrc[4];
  const unsigned short* bsrc[2];
#pragma unroll
  for (int l = 0; l < 4; ++l) asrc[l] = A  + (size_t)(m0 + l * 64 + srow) * KC + sc * 8;
#pragma unroll
  for (int l = 0; l < 2; ++l) bsrc[l] = Bw + (size_t)(n0 + l * 64 + srow) * KC + sc * 8;

  const int x7 = ln15 & 7;
  const int slA0 = (lq ^ x7) * 8;
  const int slA1 = ((4 + lq) ^ x7) * 8;
  int rA[4], rB[4];
#pragma unroll
  for (int i = 0; i < 4; ++i) rA[i] = (wm * 64 + i * 16 + ln15) * 64;
#pragma unroll
  for (int j = 0; j < 4; ++j) rB[j] = (wn * 64 + j * 16 + ln15) * 64;

  constexpr int NT = KC / 64;   // 32
  auto stA = [&](int kt, int buf, int l) {
    gload_lds16(asrc[l] + (size_t)kt * 64, &Al[buf][(size_t)(l * 512 + w * 64) * 8]);
  };
  auto stB = [&](int kt, int buf, int l) {
    gload_lds16(bsrc[l] + (size_t)kt * 64, &Bl[buf][(size_t)(l * 512 + w * 64) * 8]);
  };

  // prologue: stage tiles 0,1 (6 loads each); wait tile0; barrier
  stA(0, 0, 0); stA(0, 0, 1); stA(0, 0, 2); stA(0, 0, 3); stB(0, 0, 0); stB(0, 0, 1);
  stA(1, 1, 0); stA(1, 1, 1); stA(1, 1, 2); stA(1, 1, 3); stB(1, 1, 0); stB(1, 1, 1);
  WAITV6; BARX;

  f32x4 acc[4][4] = {};
  int cb = 0, nb = 2;
  for (int kt = 0; kt < NT; ++kt) {
    const unsigned short* Ac = &Al[cb][0];
    const unsigned short* Bc = &Bl[cb][0];
    const bool pf = (kt + 2 < NT);
    short8 a01[2][2], a23[2][2], bf[4][2];

    // ---- phase 0: read A(m0,m1)+B(all), stage 3 A-halves of kt+2 ----
#pragma unroll
    for (int i = 0; i < 2; ++i) {
      a01[i][0] = *(const short8*)&Ac[rA[i] + slA0];
      a01[i][1] = *(const short8*)&Ac[rA[i] + slA1];
    }
#pragma unroll
    for (int j = 0; j < 4; ++j) {
      bf[j][0] = *(const short8*)&Bc[rB[j] + slA0];
      bf[j][1] = *(const short8*)&Bc[rB[j] + slA1];
    }
    if (pf) { stA(kt + 2, nb, 0); stA(kt + 2, nb, 1); stA(kt + 2, nb, 2); }
    BARX;
    WAITL0; SCHED0;
    __builtin_amdgcn_s_setprio(1);
#pragma unroll
    for (int i = 0; i < 2; ++i)
#pragma unroll
      for (int j = 0; j < 4; ++j)
#pragma unroll
        for (int k = 0; k < 2; ++k)
          acc[i][j] = __builtin_amdgcn_mfma_f32_16x16x32_bf16(a01[i][k], bf[j][k], acc[i][j], 0, 0, 0);
    __builtin_amdgcn_s_setprio(0);
    BARX;

    // ---- phase 1: read A(m2,m3), stage A3+B0+B1 of kt+2, 16 MFMA, vmcnt ----
#pragma unroll
    for (int i = 0; i < 2; ++i) {
      a23[i][0] = *(const short8*)&Ac[rA[2 + i] + slA0];
      a23[i][1] = *(const short8*)&Ac[rA[2 + i] + slA1];
    }
    if (pf) { stA(kt + 2, nb, 3); stB(kt + 2, nb, 0); stB(kt + 2, nb, 1); }
    BARX;
    WAITL0; SCHED0;
    __builtin_amdgcn_s_setprio(1);
#pragma unroll
    for (int i = 0; i < 2; ++i)
#pragma unroll
      for (int j = 0; j < 4; ++j)
#pragma unroll
        for (int k = 0; k < 2; ++k)
          acc[2 + i][j] = __builtin_amdgcn_mfma_f32_16x16x32_bf16(a23[i][k], bf[j][k], acc[2 + i][j], 0, 0, 0);
    __builtin_amdgcn_s_setprio(0);
    if (kt < NT - 2) { WAITV6; }
    else if (kt == NT - 2) { WAITV0; }
    BARX;

    cb = (cb == 2) ? 0 : cb + 1;
    nb = (nb == 2) ? 0 : nb + 1;
  }

  // ---- epilogue ----
  if (EPI == 0) {
#pragma unroll
    for (int i = 0; i < 4; ++i)
#pragma unroll
      for (int j = 0; j < 4; ++j) {
        int colb = n0 + wn * 64 + j * 16;         // + ln15
        int z = colb >> 11;
        int c2 = (colb & 2047) + ln15;
        int h = c2 >> 7, d = c2 & 127;
        int m = m0 + wm * 64 + i * 16 + lq * 4;   // + rr
        int b = m >> 11, s = m & 2047;
        if (z == 2) {
          us4 pk;
#pragma unroll
          for (int r = 0; r < 4; ++r) pk[r] = f2bf(acc[i][j][r]);
          *(us4*)((unsigned short*)dv + (((size_t)b * NHc + h) * HDc + d) * SS + s) = pk;
        } else {
          unsigned short* D = (unsigned short*)(z ? dk : dq);
#pragma unroll
          for (int r = 0; r < 4; ++r)
            D[(((size_t)b * NHc + h) * SS + s + r) * HDc + d] = f2bf(acc[i][j][r]);
        }
      }
  } else {
    float* O = (float*)dq;
#pragma unroll
    for (int i = 0; i < 4; ++i)
#pragma unroll
      for (int j = 0; j < 4; ++j) {
        int col = n0 + wn * 64 + j * 16 + ln15;
        int m = m0 + wm * 64 + i * 16 + lq * 4;
#pragma unroll
        for (int r = 0; r < 4; ++r)
          O[(size_t)(m + r) * HIDc + col] = acc[i][j][r];
      }
  }
}

// ---------------------------------------------------------------------------
// 4) in-place interleaved RoPE on Q and K
// ---------------------------------------------------------------------------
__global__ void __launch_bounds__(256) rope_kernel(
    unsigned int* __restrict__ Q, unsigned int* __restrict__ Kd,
    const float* __restrict__ cosT, const float* __restrict__ sinT)
{
  constexpr size_t NP = (size_t)BB * NHc * SS * 64;   // pairs per tensor
  size_t gid = (size_t)blockIdx.x * 256 + threadIdx.x;
  unsigned int* P = (gid < NP) ? Q : Kd;
  size_t r = (gid < NP) ? gid : gid - NP;
  int j  = (int)(r & 63);
  int s  = (int)((r >> 6) & (SS - 1));
  int fi = j & 31;
  float c  = cosT[s * 32 + fi];
  float sn = sinT[s * 32 + fi];
  unsigned v = P[r];
  float x1 = bf2f((unsigned short)(v & 0xffff));
  float x2 = bf2f((unsigned short)(v >> 16));
  float y1 = x1 * c - x2 * sn;
  float y2 = x1 * sn + x2 * c;
  P[r] = (unsigned)f2bf(y1) | ((unsigned)f2bf(y2) << 16);
}

// ---------------------------------------------------------------------------
// 5) causal flash attention (v6 structure, unchanged)
// ---------------------------------------------------------------------------
__global__ void __launch_bounds__(256) attn_kernel(
    const unsigned short* __restrict__ Qg,
    const unsigned short* __restrict__ Kg,
    const unsigned short* __restrict__ Vg,   // [b][h][d][s]
    unsigned short* __restrict__ Og)
{
  __shared__ __align__(16) unsigned short Klds[2][64 * 128];   // [kv][d] swizzled
  __shared__ __align__(16) unsigned short Vlds[2][128 * 64];   // [d][kv] swizzled
  __shared__ __align__(16) unsigned short Plds[4][32 * 64];    // per-wave [q][kv] swizzled
  const int tid = threadIdx.x, lane = tid & 63, w = tid >> 6;
  const int l31 = lane & 31, hi = lane >> 5;

  const int wg = blockIdx.x;
  const int xcd = wg & 7, idx = wg >> 3;
  const int bh = xcd + 8 * (idx & 3);
  const int t  = idx >> 2;                   // 0..15 (pair id)

  const int qtile = (w < 2) ? t : (31 - t);
  const int sub1 = w & 1;
  const int q0w = qtile * 64 + sub1 * 32;
  const int ntiles = 32 - t;

  const size_t hbase = (size_t)bh * SS * HDc;
  const float CE = 1.44269504089f * 0.08838834764831845f;  // log2(e)/sqrt(128)

  short8 qf[8];
#pragma unroll
  for (int ks = 0; ks < 8; ++ks)
    qf[ks] = *(const short8*)(Qg + hbase + (size_t)(q0w + l31) * HDc + ks * 16 + hi * 8);

  f32x16 accO[4];
#pragma unroll
  for (int db = 0; db < 4; ++db)
#pragma unroll
    for (int r = 0; r < 16; ++r) accO[db][r] = 0.f;
  float mr = -1e30f, lr = 0.f;

  auto stage = [&](int kvt, int buf) {
    const int kv0 = kvt * 64;
#pragma unroll
    for (int p = 0; p < 4; ++p) {
      int c = p * 256 + w * 64 + lane;
      int krow = c >> 4, ksl = c & 15;
      gload_lds16(Kg + hbase + (size_t)(kv0 + krow) * HDc + ((ksl ^ (krow & 7)) << 3),
                  (unsigned short*)&Klds[buf][0] + (size_t)(p * 256 + w * 64) * 8);
      int vd = c >> 3, vsl = c & 7;
      gload_lds16(Vg + hbase + (size_t)vd * SS + kv0 + ((vsl ^ (vd & 7)) << 3),
                  (unsigned short*)&Vlds[buf][0] + (size_t)(p * 256 + w * 64) * 8);
    }
  };

  stage(0, 0);
  __syncthreads();
  int cur = 0;
  for (int kvt = 0; kvt < ntiles; ++kvt) {
    if (kvt + 1 < ntiles) stage(kvt + 1, cur ^ 1);

    if (kvt <= qtile) {
      const bool diag = (kvt == qtile);
      const bool haveT1 = (!diag) || sub1;

      f32x16 s0, s1;
#pragma unroll
      for (int r = 0; r < 16; ++r) s0[r] = 0.f;
      __builtin_amdgcn_s_setprio(1);
#pragma unroll
      for (int ks = 0; ks < 8; ++ks) {
        int row = l31;
        short8 kf = *(const short8*)&Klds[cur][row * 128 + (((2 * ks + hi) ^ (row & 7)) << 3)];
        s0 = __builtin_amdgcn_mfma_f32_32x32x16_bf16(kf, qf[ks], s0, 0, 0, 0);
      }
      if (haveT1) {
#pragma unroll
        for (int r = 0; r < 16; ++r) s1[r] = 0.f;
#pragma unroll
        for (int ks = 0; ks < 8; ++ks) {
          int row = 32 + l31;
          short8 kf = *(const short8*)&Klds[cur][row * 128 + (((2 * ks + hi) ^ (row & 7)) << 3)];
          s1 = __builtin_amdgcn_mfma_f32_32x32x16_bf16(kf, qf[ks], s1, 0, 0, 0);
        }
      }
      __builtin_amdgcn_s_setprio(0);

      if (diag) {
        if (sub1) {
#pragma unroll
          for (int r = 0; r < 16; ++r)
            if (((r & 3) + 8 * (r >> 2) + 4 * hi) > l31) s1[r] = -1e30f;
        } else {
#pragma unroll
          for (int r = 0; r < 16; ++r)
            if (((r & 3) + 8 * (r >> 2) + 4 * hi) > l31) s0[r] = -1e30f;
        }
      }

      float pmax = s0[0];
#pragma unroll
      for (int r = 1; r < 16; ++r) pmax = fmaxf(pmax, s0[r]);
      if (haveT1) {
#pragma unroll
        for (int r = 0; r < 16; ++r) pmax = fmaxf(pmax, s1[r]);
      }
      pmax = fmaxf(pmax, __shfl_xor(pmax, 32));

      int grow = (CE * (pmax - mr) > 8.0f) ? 1 : 0;
      if (__any(grow)) {
        float mn = fmaxf(mr, pmax);
        float al = exp2f(CE * (mr - mn));
        mr = mn; lr *= al;
        float alr[16];
#pragma unroll
        for (int r = 0; r < 16; ++r)
          alr[r] = __shfl(al, (r & 3) + 8 * (r >> 2) + 4 * hi);
#pragma unroll
        for (int db = 0; db < 4; ++db)
#pragma unroll
          for (int r = 0; r < 16; ++r) accO[db][r] *= alr[r];
      }

      float psum = 0.f;
#pragma unroll
      for (int r = 0; r < 16; ++r) {
        float p = exp2f(CE * (s0[r] - mr));
        s0[r] = p; psum += p;
      }
      if (haveT1) {
#pragma unroll
        for (int r = 0; r < 16; ++r) {
          float p = exp2f(CE * (s1[r] - mr));
          s1[r] = p; psum += p;
        }
      }
      psum += __shfl_xor(psum, 32);
      lr += psum;

#pragma unroll
      for (int i = 0; i < 8; ++i) {
        int kv = (i & 1) * 2 + (i >> 1) * 8 + 4 * hi;
        unsigned pk = cvtpk_bf16(s0[2 * i], s0[2 * i + 1]);
        *(unsigned*)&Plds[w][l31 * 64 + (((kv >> 3) ^ (l31 & 7)) << 3) + (kv & 7)] = pk;
      }
      if (haveT1) {
#pragma unroll
        for (int i = 0; i < 8; ++i) {
          int kv = 32 + (i & 1) * 2 + (i >> 1) * 8 + 4 * hi;
          unsigned pk = cvtpk_bf16(s1[2 * i], s1[2 * i + 1]);
          *(unsigned*)&Plds[w][l31 * 64 + (((kv >> 3) ^ (l31 & 7)) << 3) + (kv & 7)] = pk;
        }
      }

      short8 ap[4];
#pragma unroll
      for (int ks = 0; ks < 2; ++ks)
        ap[ks] = *(const short8*)&Plds[w][l31 * 64 + (((2 * ks + hi) ^ (l31 & 7)) << 3)];
      if (haveT1) {
#pragma unroll
        for (int ks = 2; ks < 4; ++ks)
          ap[ks] = *(const short8*)&Plds[w][l31 * 64 + (((2 * ks + hi) ^ (l31 & 7)) << 3)];
      }

      __builtin_amdgcn_s_setprio(1);
#pragma unroll
      for (int db = 0; db < 4; ++db) {
        int row = db * 32 + l31;
#pragma unroll
        for (int ks = 0; ks < 2; ++ks) {
          short8 vf = *(const short8*)&Vlds[cur][row * 64 + (((2 * ks + hi) ^ (row & 7)) << 3)];
          accO[db] = __builtin_amdgcn_mfma_f32_32x32x16_bf16(ap[ks], vf, accO[db], 0, 0, 0);
        }
      }
      if (haveT1) {
#pragma unroll
        for (int db = 0; db < 4; ++db) {
          int row = db * 32 + l31;
#pragma unroll
          for (int ks = 2; ks < 4; ++ks) {
            short8 vf = *(const short8*)&Vlds[cur][row * 64 + (((2 * ks + hi) ^ (row & 7)) << 3)];
            accO[db] = __builtin_amdgcn_mfma_f32_32x32x16_bf16(ap[ks], vf, accO[db], 0, 0, 0);
          }
        }
      }
      __builtin_amdgcn_s_setprio(0);
    }

    __syncthreads();
    cur ^= 1;
  }

  float il = 1.0f / lr;
  float ilr[16];
#pragma unroll
  for (int r = 0; r < 16; ++r)
    ilr[r] = __shfl(il, (r & 3) + 8 * (r >> 2) + 4 * hi);
  const int b = bh >> 4, h = bh & 15;
#pragma unroll
  for (int db = 0; db < 4; ++db)
#pragma unroll
    for (int r = 0; r < 16; ++r) {
      int q = q0w + (r & 3) + 8 * (r >> 2) + 4 * hi;
      int d = db * 32 + l31;
      Og[((size_t)b * SS + q) * HIDc + h * HDc + d] = f2bf(accO[db][r] * ilr[r]);
    }
}

// ---------------------------------------------------------------------------
extern "C" void kernel_launch(void* const* d_in, const int* in_sizes, int n_in,
                              void* d_out, int out_size, void* d_ws, size_t ws_size,
                              hipStream_t stream)
{
  if (ws_size < WS_NEED) return;

  const float* H  = (const float*)d_in[0];
  const float* Wq = (const float*)d_in[1];
  const float* Wk = (const float*)d_in[2];
  const float* Wv = (const float*)d_in[3];
  const float* Wo = (const float*)d_in[4];
  char* ws = (char*)d_ws;
  unsigned short* HB = (unsigned short*)(ws + OFF_HB);
  unsigned short* WB = (unsigned short*)(ws + OFF_WB);
  unsigned short* Qb = (unsigned short*)(ws + OFF_Q);
  unsigned short* Kb = (unsigned short*)(ws + OFF_K);
  unsigned short* Vb = (unsigned short*)(ws + OFF_V);
  unsigned short* AT = (unsigned short*)(ws + OFF_ATT);
  float* cosT = (float*)(ws + OFF_COS);
  float* sinT = (float*)(ws + OFF_SIN);

  cvt_kernel<<<12288, 256, 0, stream>>>(H, Wq, Wk, Wv, Wo, HB);
  rope_tab_kernel<<<256, 256, 0, stream>>>(cosT, sinT);
  // QKV: folded N = 6144 (WB = [Wq;Wk;Wv]) -> grid 8 XCD * 2 by * 48 bx = 768
  gemm8<0, 48><<<768, 512, 0, stream>>>(HB, WB, Qb, Kb, Vb);
  rope_kernel<<<32768, 256, 0, stream>>>((unsigned*)Qb, (unsigned*)Kb, cosT, sinT);
  attn_kernel<<<512, 256, 0, stream>>>(Qb, Kb, Vb, AT);
  // proj: N = 2048 -> grid 8 * 2 * 16 = 256
  gemm8<1, 16><<<256, 512, 0, stream>>>(AT, WB + (size_t)3 * HIDc * KC,
                                        d_out, nullptr, nullptr);
}